// Round 6
// baseline (1500.708 us; speedup 1.0000x reference)
//
#include <hip/hip_runtime.h>
#include <hip/hip_bf16.h>

#ifndef __has_builtin
#define __has_builtin(x) 0
#endif

#define N_NODES 30000
#define N_EDGES 510000
#define K_DIM   128
#define ABLK    7500   // scat node-blocks per snapshot (4 nodes/block)
#define EBLK    997    // edge-kernel blocks per snapshot: ceil(510000/512)
#define FB1     15000  // fuse1 blocks: N*128/256
#define FB2     7500   // fuse2 blocks: N*64/256

typedef short bf16x8 __attribute__((ext_vector_type(8)));
typedef float f32x4  __attribute__((ext_vector_type(4)));
typedef float f32x2  __attribute__((ext_vector_type(2)));
typedef unsigned int u32x2 __attribute__((ext_vector_type(2)));
typedef short s16x2 __attribute__((ext_vector_type(2)));

__device__ __forceinline__ unsigned short f2bf(float f) {
  __hip_bfloat16 h = __float2bfloat16(f);
  return *(unsigned short*)&h;
}
__device__ __forceinline__ float bf2f(unsigned short u) {
  __hip_bfloat16 h = *(__hip_bfloat16*)&u;
  return __bfloat162float(h);
}

// packed bf16x2 atomic add to global (L2-resident, address-striped across XCDs)
__device__ __forceinline__ void atom_pk_bf16(unsigned int* addr, float lo, float hi) {
  __hip_bfloat162 b2(__float2bfloat16(lo), __float2bfloat16(hi));
#if __has_builtin(__builtin_amdgcn_global_atomic_fadd_v2bf16)
  union { __hip_bfloat162 b; s16x2 v; } u;
  u.b = b2;
  __builtin_amdgcn_global_atomic_fadd_v2bf16(
      (__attribute__((address_space(1))) s16x2*)addr, u.v);
#else
  unsafeAtomicAdd((__hip_bfloat162*)addr, b2);
#endif
}

// ---------------- both W transposes (K x M fp32) -> (M x K bf16) ----------------
__global__ void transpose_w_kernel(const float* __restrict__ W1, unsigned short* __restrict__ Wt1,
                                   const float* __restrict__ W2, unsigned short* __restrict__ Wt2) {
  int i = blockIdx.x * blockDim.x + threadIdx.x;
  if (i < 128 * 256) {
    int k = i >> 8, m = i & 255;
    Wt1[m * 128 + k] = f2bf(W1[i]);
  } else if (i < 128 * 256 + 128 * 128) {
    int j = i - 128 * 256;
    int k = j >> 7, m = j & 127;
    Wt2[m * 128 + k] = f2bf(W2[j]);
  }
}

// ---------------- degrees: in-degree (for 1/deg) + out-degree (for src-CSR) ----------------
__global__ void deg_kernel(const int* __restrict__ ei,
                           int* __restrict__ deg0, int* __restrict__ deg1,
                           int* __restrict__ degS0, int* __restrict__ degS1, int e) {
  int i = blockIdx.x * blockDim.x + threadIdx.x;
  if (i < 2 * e) {
    int t = i >= e ? 1 : 0;
    int j = i - t * e;
    int s = ei[(size_t)t * 2 * e + j];
    int d = ei[(size_t)t * 2 * e + e + j];
    atomicAdd(&(t ? deg1 : deg0)[d], 1);
    atomicAdd(&(t ? degS1 : degS0)[s], 1);
  }
}

// ---------------- exclusive scan of OUT-degree + rn=1/in-deg, one block per snapshot ----------------
__global__ __launch_bounds__(1024) void scan_kernel(const int* __restrict__ degS0, int* __restrict__ offS0, int* __restrict__ curS0,
                                                    const int* __restrict__ degS1, int* __restrict__ offS1, int* __restrict__ curS1,
                                                    const int* __restrict__ deg0, float* __restrict__ rn0,
                                                    const int* __restrict__ deg1, float* __restrict__ rn1,
                                                    int n) {
  const int* degS = blockIdx.x ? degS1 : degS0;
  int* off = blockIdx.x ? offS1 : offS0;
  int* cur = blockIdx.x ? curS1 : curS0;
  const int* deg = blockIdx.x ? deg1 : deg0;
  float* rn = blockIdx.x ? rn1 : rn0;
  const int CHUNK = 30;  // 1024*30 >= 30000
  __shared__ int wsum[16];
  int tid = threadIdx.x;
  int base = tid * CHUNK;
  int sum = 0;
  for (int i = 0; i < CHUNK; i++)
    if (base + i < n) sum += degS[base + i];
  int lane = tid & 63, wid = tid >> 6;
  int incl = sum;
#pragma unroll
  for (int o = 1; o < 64; o <<= 1) {
    int v = __shfl_up(incl, o);
    if (lane >= o) incl += v;
  }
  if (lane == 63) wsum[wid] = incl;
  __syncthreads();
  if (tid == 0) {
    int run = 0;
    for (int w = 0; w < 16; w++) { int v = wsum[w]; wsum[w] = run; run += v; }
  }
  __syncthreads();
  int run = incl - sum + wsum[wid];
  for (int i = 0; i < CHUNK; i++) {
    if (base + i < n) {
      int dg = degS[base + i];
      off[base + i] = run;
      cur[base + i] = run;
      rn[base + i] = 1.0f / (float)deg[base + i];   // in-deg >= 1 (self-loop)
      run += dg;
    }
  }
}

// ---------------- scatter edges into SRC-major CSR packed {src|dst<<16} ----------------
// src,dst < 30000 < 2^15, so u16 packing is exact.
__global__ void scatter_kernel(const int* __restrict__ ei,
                               int* __restrict__ curS0, int* __restrict__ curS1,
                               unsigned int* __restrict__ csrS0, unsigned int* __restrict__ csrS1, int e) {
  int i = blockIdx.x * blockDim.x + threadIdx.x;
  if (i < 2 * e) {
    int t = i >= e ? 1 : 0;
    int j = i - t * e;
    int s = ei[(size_t)t * 2 * e + j];
    int d = ei[(size_t)t * 2 * e + e + j];
    int* cur = t ? curS1 : curS0;
    unsigned int* csr = t ? csrS1 : csrS0;
    int p = atomicAdd(&cur[s], 1);
    csr[p] = (unsigned int)s | ((unsigned int)d << 16);
  }
}

// ---------------- fused GEMM + fp8-H write + per-node attention scores (both t) ----------------
template<int M, bool F32IN>
__global__ __launch_bounds__(256) void gemm_kernel(const void* __restrict__ X0v,
                                                   const void* __restrict__ X1v,
                                                   const short* __restrict__ Wt,
                                                   unsigned char* __restrict__ H0,
                                                   unsigned char* __restrict__ H1,
                                                   const float* __restrict__ att,
                                                   float* __restrict__ si0, float* __restrict__ si1,
                                                   float* __restrict__ sj0, float* __restrict__ sj1,
                                                   int nrows) {
  int t = blockIdx.y;
  const void* Xv = t ? X1v : X0v;
  unsigned char* Hf8 = t ? H1 : H0;
  float* s_i = t ? si1 : si0;
  float* s_j = t ? sj1 : sj0;

  int wave = blockIdx.x * 4 + (threadIdx.x >> 6);
  int lane = threadIdx.x & 63;
  if (wave * 16 >= nrows) return;
  int m16 = lane & 15, quad = lane >> 4;

  bf16x8 a[4];
  size_t arow = (size_t)(wave * 16 + m16) * K_DIM + quad * 8;
  if constexpr (F32IN) {
    const float* X = (const float*)Xv;
#pragma unroll
    for (int kc = 0; kc < 4; kc++) {
      f32x4 lo = *(const f32x4*)(X + arow + kc * 32);
      f32x4 hi = *(const f32x4*)(X + arow + kc * 32 + 4);
#pragma unroll
      for (int j = 0; j < 4; j++) {
        ((unsigned short*)&a[kc])[j]     = f2bf(lo[j]);
        ((unsigned short*)&a[kc])[4 + j] = f2bf(hi[j]);
      }
    }
  } else {
    const short* X = (const short*)Xv;
#pragma unroll
    for (int kc = 0; kc < 4; kc++) a[kc] = *(const bf16x8*)(X + arow + kc * 32);
  }

  float sip[4] = {0.f, 0.f, 0.f, 0.f}, sjp[4] = {0.f, 0.f, 0.f, 0.f};
#pragma unroll
  for (int nt = 0; nt < M / 16; nt++) {
    f32x4 acc = {0.f, 0.f, 0.f, 0.f};
    size_t brow = (size_t)(nt * 16 + m16) * K_DIM + quad * 8;
#pragma unroll
    for (int kc = 0; kc < 4; kc++) {
      bf16x8 b = *(const bf16x8*)(Wt + brow + kc * 32);
      acc = __builtin_amdgcn_mfma_f32_16x16x32_bf16(a[kc], b, acc, 0, 0, 0);
    }
    int col = nt * 16 + m16;
    float aA = att[col], aB = att[M + col];
#pragma unroll
    for (int r = 0; r < 4; r++) {
      int row = wave * 16 + quad * 4 + r;
      // hardware fp8 (OCP e4m3) convert — avoids software __hip_fp8 ctor path
      int pk = __builtin_amdgcn_cvt_pk_fp8_f32(acc[r], acc[r], 0, false);
      Hf8[(size_t)row * M + col] = (unsigned char)pk;
      sip[r] += acc[r] * aA;
      sjp[r] += acc[r] * aB;
    }
  }
#pragma unroll
  for (int o = 1; o < 16; o <<= 1) {
#pragma unroll
    for (int r = 0; r < 4; r++) {
      sip[r] += __shfl_xor(sip[r], o);
      sjp[r] += __shfl_xor(sjp[r], o);
    }
  }
  if (m16 == 0) {
#pragma unroll
    for (int r = 0; r < 4; r++) {
      int row = wave * 16 + quad * 4 + r;
      s_i[row] = sip[r];
      s_j[row] = sjp[r];
    }
  }
}

// ---------------- edge-parallel alpha precompute (src-major order) + skl partials ----------------
// Per CSR position: p = clip(sigmoid(leaky(si[dst]+sj[src]))), w = p/deg[dst],
// writes packed {dst, w} (8B) consumed by scat; skl accumulated per block.
__global__ __launch_bounds__(256) void edge_kernel(const unsigned int* __restrict__ csr_0,
                                                   const unsigned int* __restrict__ csr_1,
                                                   const float* __restrict__ rn0, const float* __restrict__ rn1,
                                                   const float* __restrict__ si0, const float* __restrict__ si1,
                                                   const float* __restrict__ sj0, const float* __restrict__ sj1,
                                                   u32x2* __restrict__ iw0, u32x2* __restrict__ iw1,
                                                   float* __restrict__ epart,  // [2*EBLK]
                                                   int e) {
  int t = blockIdx.y;
  const unsigned int* csr = t ? csr_1 : csr_0;
  const float* rn = t ? rn1 : rn0;
  const float* s_i = t ? si1 : si0;
  const float* s_j = t ? sj1 : sj0;
  u32x2* iw = t ? iw1 : iw0;

  const float q   = 1.0f / (1.0f + __expf(-(1.0f / 15.0f)));
  const float lq  = __logf(q);
  const float l1q = __logf(1.0f - q);

  __shared__ float red[4];
  float skl = 0.f;
  int p0 = (blockIdx.x * 256 + threadIdx.x) * 2;
#pragma unroll
  for (int u = 0; u < 2; u++) {
    int p = p0 + u;
    if (p < e) {
      unsigned int sd = csr[p];
      int s = (int)(sd & 0xffffu);
      int dd = (int)(sd >> 16);
      float lg = s_i[dd] + s_j[s];
      lg = lg > 0.f ? lg : 0.2f * lg;                 // leaky_relu
      float pv = 1.0f / (1.0f + __expf(-lg));        // sigmoid
      pv = fminf(fmaxf(pv, 0.01f), 0.99f);           // clip
      skl += pv * (__logf(pv) - lq) + (1.0f - pv) * (__logf(1.0f - pv) - l1q);
      float w = pv * rn[dd];                          // fold 1/deg into alpha
      u32x2 o;
      o[0] = (unsigned int)dd;
      o[1] = __float_as_uint(w);
      iw[p] = o;
    }
  }
  int lane = threadIdx.x & 63, wid = threadIdx.x >> 6;
#pragma unroll
  for (int o = 32; o > 0; o >>= 1) skl += __shfl_xor(skl, o);
  if (lane == 0) red[wid] = skl;
  __syncthreads();
  if (threadIdx.x == 0) epart[t * EBLK + blockIdx.x] = red[0] + red[1] + red[2] + red[3];
}

// ---------------- src-major SCATTER aggregation ----------------
// One wave per SRC node: H row loaded once (sequential, 64 lanes), decoded to regs;
// per out-edge: readlane dst/w -> packed bf16 atomic add into A[dst] (wave-uniform
// row address, lanes = channels, coalesced; A is L2-resident: 1/8 per XCD = 3.8 MB).
template<int M>  // M = 2C
__global__ __launch_bounds__(256) void scat_kernel(const unsigned char* __restrict__ H0,
                                                   const unsigned char* __restrict__ H1,
                                                   const u32x2* __restrict__ iw0, const u32x2* __restrict__ iw1,
                                                   const int* __restrict__ offS0, const int* __restrict__ offS1,
                                                   const int* __restrict__ degS0, const int* __restrict__ degS1,
                                                   unsigned short* __restrict__ A0, unsigned short* __restrict__ A1v,
                                                   int n) {
  int t = blockIdx.y;
  const unsigned char* Hf8 = t ? H1 : H0;
  const u32x2* iw = t ? iw1 : iw0;
  const int* offS = t ? offS1 : offS0;
  const int* degS = t ? degS1 : degS0;
  unsigned int* A = (unsigned int*)(t ? A1v : A0);   // bf16-pair granularity

  int wid = threadIdx.x >> 6, lane = threadIdx.x & 63;
  int s = blockIdx.x * 4 + wid;
  if (s >= n) return;
  int d     = __builtin_amdgcn_readfirstlane(degS[s]);
  int start = __builtin_amdgcn_readfirstlane(offS[s]);

  // load + decode this src's H row (held in registers for all its out-edges)
  float h0, h1, h2 = 0.f, h3 = 0.f;
  if constexpr (M == 256) {
    unsigned int hv = *(const unsigned int*)(Hf8 + (size_t)s * M + lane * 4);
    f32x2 lo = __builtin_amdgcn_cvt_pk_f32_fp8((int)hv, false);
    f32x2 hi = __builtin_amdgcn_cvt_pk_f32_fp8((int)hv, true);
    h0 = lo[0]; h1 = lo[1]; h2 = hi[0]; h3 = hi[1];
  } else {
    unsigned int hv = *(const unsigned short*)(Hf8 + (size_t)s * M + lane * 2);
    f32x2 lo = __builtin_amdgcn_cvt_pk_f32_fp8((int)hv, false);
    h0 = lo[0]; h1 = lo[1];
  }

  const u32x2* iwp = iw + start;
  for (int e0 = 0; e0 < d; e0 += 64) {
    int ee = e0 + lane;
    u32x2 iwv = iwp[ee < d ? ee : d - 1];
    int cnt = min(d - e0, 64);
    for (int e = 0; e < cnt; e++) {
      int dst = __builtin_amdgcn_readlane((int)iwv[0], e);
      float w = __uint_as_float(__builtin_amdgcn_readlane((int)iwv[1], e));
      if constexpr (M == 256) {
        unsigned int* row = A + (size_t)dst * (M / 2);     // 128 bf16-pairs per row
        atom_pk_bf16(row + lane * 2,     h0 * w, h1 * w);  // ch 4l, 4l+1
        atom_pk_bf16(row + lane * 2 + 1, h2 * w, h3 * w);  // ch 4l+2, 4l+3
      } else {
        atom_pk_bf16(A + (size_t)dst * (M / 2) + lane, h0 * w, h1 * w);  // ch 2l, 2l+1
      }
    }
  }
}

// ---------------- layer-1 epilogue: bias + ixz + temporal fusion + ReLU -> bf16 x2 ----------------
__global__ __launch_bounds__(256) void fuse1_kernel(const unsigned short* __restrict__ A0,
                                                    const unsigned short* __restrict__ A1v,
                                                    const float* __restrict__ b,
                                                    __hip_bfloat16* __restrict__ x0,
                                                    __hip_bfloat16* __restrict__ x1,
                                                    float* __restrict__ apart) {  // [FB1]
  __shared__ float red[4];
  int i = blockIdx.x * 256 + threadIdx.x;        // i < N*128 exactly
  int v = i >> 7, c = i & 127;
  float bm = b[c], bs = b[128 + c];
  const unsigned short* r0 = A0 + (size_t)v * 256;
  const unsigned short* r1 = A1v + (size_t)v * 256;
  float a0m = bf2f(r0[c]) + bm, a0s = bf2f(r0[128 + c]) + bs;
  float a1m = bf2f(r1[c]) + bm, a1s = bf2f(r1[128 + c]) + bs;
  float sp0 = (a0s > 20.f) ? a0s : log1pf(__expf(a0s)); sp0 += 1e-10f;
  float sp1 = (a1s > 20.f) ? a1s : log1pf(__expf(a1s)); sp1 += 1e-10f;
  float ixz = 0.5f * (a0m * a0m + a1m * a1m) - 1.0f
            - __logf(sp0) + 0.5f * sp0 * sp0
            - __logf(sp1) + 0.5f * sp1 * sp1;
  x0[(size_t)v * 128 + c] = __float2bfloat16(fmaxf(a0m, 0.f));
  x1[(size_t)v * 128 + c] = __float2bfloat16(fmaxf(0.4f * a0m + 0.2f * a1m, 0.f));
  int lane = threadIdx.x & 63, wid = threadIdx.x >> 6;
#pragma unroll
  for (int o = 32; o > 0; o >>= 1) ixz += __shfl_xor(ixz, o);
  if (lane == 0) red[wid] = ixz;
  __syncthreads();
  if (threadIdx.x == 0) apart[blockIdx.x] = red[0] + red[1] + red[2] + red[3];
}

// ---------------- layer-2 epilogue: bias + ixz + temporal fusion -> final fp32 out ----------------
__global__ __launch_bounds__(256) void fuse2_kernel(const unsigned short* __restrict__ A0,
                                                    const unsigned short* __restrict__ A1v,
                                                    const float* __restrict__ b,
                                                    float* __restrict__ out,
                                                    float* __restrict__ apart) {  // [FB2]
  __shared__ float red[4];
  int i = blockIdx.x * 256 + threadIdx.x;        // i < N*64 exactly
  int v = i >> 6, c = i & 63;
  float bm = b[c], bs = b[64 + c];
  const unsigned short* r0 = A0 + (size_t)v * 128;
  const unsigned short* r1 = A1v + (size_t)v * 128;
  float a0m = bf2f(r0[c]) + bm, a0s = bf2f(r0[64 + c]) + bs;
  float a1m = bf2f(r1[c]) + bm, a1s = bf2f(r1[64 + c]) + bs;
  float sp0 = (a0s > 20.f) ? a0s : log1pf(__expf(a0s)); sp0 += 1e-10f;
  float sp1 = (a1s > 20.f) ? a1s : log1pf(__expf(a1s)); sp1 += 1e-10f;
  float ixz = 0.5f * (a0m * a0m + a1m * a1m) - 1.0f
            - __logf(sp0) + 0.5f * sp0 * sp0
            - __logf(sp1) + 0.5f * sp1 * sp1;
  out[i] = a0m;
  out[(size_t)N_NODES * 64 + i] = 0.4f * a0m + 0.2f * a1m;
  int lane = threadIdx.x & 63, wid = threadIdx.x >> 6;
#pragma unroll
  for (int o = 32; o > 0; o >>= 1) ixz += __shfl_xor(ixz, o);
  if (lane == 0) red[wid] = ixz;
  __syncthreads();
  if (threadIdx.x == 0) apart[blockIdx.x] = red[0] + red[1] + red[2] + red[3];
}

// ---------------- final reduction of per-block partials -> scalars ----------------
__global__ __launch_bounds__(1024) void reduce_kernel(const float* __restrict__ a1,
                                                      const float* __restrict__ a2,
                                                      const float* __restrict__ e1,
                                                      const float* __restrict__ e2,
                                                      float* __restrict__ out2) {
  __shared__ float ri[16], rs[16];
  float ixz = 0.f, skl = 0.f;
  for (int i = threadIdx.x; i < FB1; i += 1024) ixz += a1[i];
  for (int i = threadIdx.x; i < FB2; i += 1024) ixz += a2[i];
  for (int i = threadIdx.x; i < 2 * EBLK; i += 1024) skl += e1[i] + e2[i];
  int lane = threadIdx.x & 63, wid = threadIdx.x >> 6;
#pragma unroll
  for (int o = 32; o > 0; o >>= 1) {
    ixz += __shfl_xor(ixz, o);
    skl += __shfl_xor(skl, o);
  }
  if (lane == 0) { ri[wid] = ixz; rs[wid] = skl; }
  __syncthreads();
  if (threadIdx.x == 0) {
    float si = 0.f, ss = 0.f;
    for (int w = 0; w < 16; w++) { si += ri[w]; ss += rs[w]; }
    out2[0] = si / (4.0f * (float)N_NODES);
    out2[1] = ss / (4.0f * (float)N_EDGES);
  }
}

extern "C" void kernel_launch(void* const* d_in, const int* in_sizes, int n_in,
                              void* d_out, int out_size, void* d_ws, size_t ws_size,
                              hipStream_t stream) {
  const float* x_all = (const float*)d_in[0];
  const int* ei      = (const int*)d_in[1];
  const float* W1    = (const float*)d_in[2];
  const float* att1  = (const float*)d_in[3];
  const float* b1    = (const float*)d_in[4];
  const float* W2    = (const float*)d_in[5];
  const float* att2  = (const float*)d_in[6];
  const float* b2    = (const float*)d_in[7];
  float* out         = (float*)d_out;

  char* ws = (char*)d_ws;
  size_t off = 0;
  auto alloc = [&](size_t bytes) {
    char* p = ws + off;
    off = (off + bytes + 255) & ~(size_t)255;
    return p;
  };
  unsigned short* wt1  = (unsigned short*)alloc(256 * 128 * sizeof(short));
  unsigned short* wt2  = (unsigned short*)alloc(128 * 128 * sizeof(short));
  unsigned char* hf8_0 = (unsigned char*)alloc((size_t)N_NODES * 256);
  unsigned char* hf8_1 = (unsigned char*)alloc((size_t)N_NODES * 256);
  float* si0   = (float*)alloc(N_NODES * sizeof(float));
  float* si1   = (float*)alloc(N_NODES * sizeof(float));
  float* sj0   = (float*)alloc(N_NODES * sizeof(float));
  float* sj1   = (float*)alloc(N_NODES * sizeof(float));
  // bf16 accumulators: A1 = 2 x [N][256] bf16 (30.7 MB). A2 (2 x [N][128]) aliases the
  // first half (A1 dead after fuse1; memset'd between fuse1 and scat2; stream-ordered).
  char* Aregion = alloc((size_t)2 * N_NODES * 256 * sizeof(short));
  unsigned short* A1_0 = (unsigned short*)Aregion;
  unsigned short* A1_1 = A1_0 + (size_t)N_NODES * 256;
  unsigned short* A2_0 = A1_0;
  unsigned short* A2_1 = A1_0 + (size_t)N_NODES * 128;
  // x2 region (2 x N*128 bf16 = 15.36 MB); iw buffers (2 x 4.08 MB) ALIAS it:
  //   edge1 writes iw -> scat1 reads iw -> fuse1 writes x2 (iw dead) ->
  //   gemm2 reads x2 -> edge2 writes iw (x2 dead) -> scat2 reads iw.  Stream-ordered.
  char* x2region = alloc((size_t)N_NODES * 256 * sizeof(short));
  __hip_bfloat16* x2_0 = (__hip_bfloat16*)x2region;
  __hip_bfloat16* x2_1 = x2_0 + (size_t)N_NODES * 128;
  u32x2* iwp[2] = {(u32x2*)x2region, (u32x2*)x2region + N_EDGES};
  int* degp[2]  = {(int*)alloc(N_NODES * 4), (int*)alloc(N_NODES * 4)};   // in-degree
  int* degSp[2] = {(int*)alloc(N_NODES * 4), (int*)alloc(N_NODES * 4)};   // out-degree
  int* offSp[2] = {(int*)alloc(N_NODES * 4), (int*)alloc(N_NODES * 4)};
  int* curSp[2] = {(int*)alloc(N_NODES * 4), (int*)alloc(N_NODES * 4)};
  float* rnp[2] = {(float*)alloc(N_NODES * 4), (float*)alloc(N_NODES * 4)};
  unsigned int* csrSp[2] = {(unsigned int*)alloc((size_t)N_EDGES * 4),
                            (unsigned int*)alloc((size_t)N_EDGES * 4)};
  float* apart1 = (float*)alloc(FB1 * sizeof(float));
  float* apart2 = (float*)alloc(FB2 * sizeof(float));
  float* epart1 = (float*)alloc(2 * EBLK * sizeof(float));
  float* epart2 = (float*)alloc(2 * EBLK * sizeof(float));

  hipMemsetAsync(degp[0], 0, N_NODES * 4, stream);
  hipMemsetAsync(degp[1], 0, N_NODES * 4, stream);
  hipMemsetAsync(degSp[0], 0, N_NODES * 4, stream);
  hipMemsetAsync(degSp[1], 0, N_NODES * 4, stream);
  hipMemsetAsync(Aregion, 0, (size_t)2 * N_NODES * 256 * sizeof(short), stream);

  transpose_w_kernel<<<192, 256, 0, stream>>>(W1, wt1, W2, wt2);

  deg_kernel<<<(2 * N_EDGES + 255) / 256, 256, 0, stream>>>(ei, degp[0], degp[1],
                                                            degSp[0], degSp[1], N_EDGES);
  scan_kernel<<<2, 1024, 0, stream>>>(degSp[0], offSp[0], curSp[0],
                                      degSp[1], offSp[1], curSp[1],
                                      degp[0], rnp[0], degp[1], rnp[1], N_NODES);
  scatter_kernel<<<(2 * N_EDGES + 255) / 256, 256, 0, stream>>>(ei, curSp[0], curSp[1],
                                                                csrSp[0], csrSp[1], N_EDGES);

  dim3 ggrid(469, 2), egrid(EBLK, 2), agrid(ABLK, 2);

  // ---- layer 1 (C = 128, M = 256) ----
  const float* x0 = x_all;
  const float* x1 = x_all + (size_t)N_NODES * K_DIM;
  gemm_kernel<256, true><<<ggrid, 256, 0, stream>>>(x0, x1, (const short*)wt1, hf8_0, hf8_1,
                                                    att1, si0, si1, sj0, sj1, N_NODES);
  edge_kernel<<<egrid, 256, 0, stream>>>(csrSp[0], csrSp[1], rnp[0], rnp[1],
                                         si0, si1, sj0, sj1, iwp[0], iwp[1], epart1, N_EDGES);
  scat_kernel<256><<<agrid, 256, 0, stream>>>(hf8_0, hf8_1, iwp[0], iwp[1], offSp[0], offSp[1],
                                              degSp[0], degSp[1], A1_0, A1_1, N_NODES);
  fuse1_kernel<<<FB1, 256, 0, stream>>>(A1_0, A1_1, b1, x2_0, x2_1, apart1);
  hipMemsetAsync(Aregion, 0, (size_t)2 * N_NODES * 128 * sizeof(short), stream);  // zero A2

  // ---- layer 2 (C = 64, M = 128) ----
  gemm_kernel<128, false><<<ggrid, 256, 0, stream>>>(x2_0, x2_1, (const short*)wt2, hf8_0, hf8_1,
                                                     att2, si0, si1, sj0, sj1, N_NODES);
  edge_kernel<<<egrid, 256, 0, stream>>>(csrSp[0], csrSp[1], rnp[0], rnp[1],
                                         si0, si1, sj0, sj1, iwp[0], iwp[1], epart2, N_EDGES);
  scat_kernel<128><<<agrid, 256, 0, stream>>>(hf8_0, hf8_1, iwp[0], iwp[1], offSp[0], offSp[1],
                                              degSp[0], degSp[1], A2_0, A2_1, N_NODES);
  fuse2_kernel<<<FB2, 256, 0, stream>>>(A2_0, A2_1, b2, out, apart2);
  reduce_kernel<<<1, 1024, 0, stream>>>(apart1, apart2, epart1, epart2, out + (size_t)2 * N_NODES * 64);
}

// Round 7
// 636.473 us; speedup vs baseline: 2.3578x; 2.3578x over previous
//
#include <hip/hip_runtime.h>
#include <hip/hip_bf16.h>

#define N_NODES 30000
#define N_EDGES 510000
#define K_DIM   128
#define ABLK    7500   // aggr node-blocks per snapshot (4 nodes/block)
#define EBLK    997    // edge-kernel blocks per snapshot: ceil(510000/512)

typedef short bf16x8 __attribute__((ext_vector_type(8)));
typedef float f32x4  __attribute__((ext_vector_type(4)));
typedef float f32x2  __attribute__((ext_vector_type(2)));
typedef unsigned int u32x2 __attribute__((ext_vector_type(2)));

__device__ __forceinline__ unsigned short f2bf(float f) {
  __hip_bfloat16 h = __float2bfloat16(f);
  return *(unsigned short*)&h;
}

// ---------------- both W transposes (K x M fp32) -> (M x K bf16) ----------------
__global__ void transpose_w_kernel(const float* __restrict__ W1, unsigned short* __restrict__ Wt1,
                                   const float* __restrict__ W2, unsigned short* __restrict__ Wt2) {
  int i = blockIdx.x * blockDim.x + threadIdx.x;
  if (i < 128 * 256) {
    int k = i >> 8, m = i & 255;
    Wt1[m * 128 + k] = f2bf(W1[i]);
  } else if (i < 128 * 256 + 128 * 128) {
    int j = i - 128 * 256;
    int k = j >> 7, m = j & 127;
    Wt2[m * 128 + k] = f2bf(W2[j]);
  }
}

// ---------------- in-degree for both snapshots ----------------
__global__ void deg_kernel(const int* __restrict__ ei, int* __restrict__ deg0,
                           int* __restrict__ deg1, int e) {
  int i = blockIdx.x * blockDim.x + threadIdx.x;
  if (i < 2 * e) {
    int t = i >= e ? 1 : 0;
    int j = i - t * e;
    int d = ei[(size_t)t * 2 * e + e + j];
    atomicAdd(&(t ? deg1 : deg0)[d], 1);
  }
}

// ---------------- exclusive scan (3-phase) + 1/deg, one block per snapshot ----------------
__global__ __launch_bounds__(1024) void scan_kernel(const int* __restrict__ deg0, int* __restrict__ off0,
                                                    int* __restrict__ cur0, float* __restrict__ rn0,
                                                    const int* __restrict__ deg1, int* __restrict__ off1,
                                                    int* __restrict__ cur1, float* __restrict__ rn1,
                                                    int n) {
  const int* deg = blockIdx.x ? deg1 : deg0;
  int* off = blockIdx.x ? off1 : off0;
  int* cur = blockIdx.x ? cur1 : cur0;
  float* rn = blockIdx.x ? rn1 : rn0;
  const int CHUNK = 30;  // 1024*30 >= 30000
  __shared__ int wsum[16];
  int tid = threadIdx.x;
  int base = tid * CHUNK;
  int sum = 0;
  for (int i = 0; i < CHUNK; i++)
    if (base + i < n) sum += deg[base + i];
  int lane = tid & 63, wid = tid >> 6;
  int incl = sum;
#pragma unroll
  for (int o = 1; o < 64; o <<= 1) {
    int v = __shfl_up(incl, o);
    if (lane >= o) incl += v;
  }
  if (lane == 63) wsum[wid] = incl;
  __syncthreads();
  if (tid == 0) {
    int run = 0;
    for (int w = 0; w < 16; w++) { int v = wsum[w]; wsum[w] = run; run += v; }
  }
  __syncthreads();
  int run = incl - sum + wsum[wid];
  for (int i = 0; i < CHUNK; i++) {
    if (base + i < n) {
      int dg = deg[base + i];
      off[base + i] = run;
      cur[base + i] = run;
      rn[base + i] = 1.0f / (float)dg;   // deg >= 1 (self-loop)
      run += dg;
    }
  }
}

// ---------------- scatter edges into dst-major CSR packed {src|dst<<16} ----------------
// src,dst < 30000 < 2^15, so u16 packing is exact.
__global__ void scatter_kernel(const int* __restrict__ ei,
                               int* __restrict__ cur0, int* __restrict__ cur1,
                               unsigned int* __restrict__ csr0, unsigned int* __restrict__ csr1, int e) {
  int i = blockIdx.x * blockDim.x + threadIdx.x;
  if (i < 2 * e) {
    int t = i >= e ? 1 : 0;
    int j = i - t * e;
    int s = ei[(size_t)t * 2 * e + j];
    int d = ei[(size_t)t * 2 * e + e + j];
    int* cur = t ? cur1 : cur0;
    unsigned int* csr = t ? csr1 : csr0;
    int p = atomicAdd(&cur[d], 1);
    csr[p] = (unsigned int)s | ((unsigned int)d << 16);
  }
}

// ---------------- fused GEMM + fp8-H write + per-node attention scores (both t) ----------------
// MODE 0: raw f32 input rows (layer 1).
// MODE 1: A-fragment built inline from layer-1 mu pair: t=0 relu(mu0); t=1 relu(.4mu0+.2mu1)
//         (replaces the former fuse1 kernel).
template<int M, int MODE>
__global__ __launch_bounds__(256) void gemm_kernel(const void* __restrict__ X0v,
                                                   const void* __restrict__ X1v,
                                                   const short* __restrict__ Wt,
                                                   unsigned char* __restrict__ H0,
                                                   unsigned char* __restrict__ H1,
                                                   const float* __restrict__ att,
                                                   float* __restrict__ si0, float* __restrict__ si1,
                                                   float* __restrict__ sj0, float* __restrict__ sj1,
                                                   int nrows) {
  int t = blockIdx.y;
  unsigned char* Hf8 = t ? H1 : H0;
  float* s_i = t ? si1 : si0;
  float* s_j = t ? sj1 : sj0;

  int wave = blockIdx.x * 4 + (threadIdx.x >> 6);
  int lane = threadIdx.x & 63;
  if (wave * 16 >= nrows) return;
  int m16 = lane & 15, quad = lane >> 4;

  bf16x8 a[4];
  size_t arow = (size_t)(wave * 16 + m16) * K_DIM + quad * 8;
  if constexpr (MODE == 0) {
    const float* X = (const float*)(t ? X1v : X0v);
#pragma unroll
    for (int kc = 0; kc < 4; kc++) {
      f32x4 lo = *(const f32x4*)(X + arow + kc * 32);
      f32x4 hi = *(const f32x4*)(X + arow + kc * 32 + 4);
#pragma unroll
      for (int j = 0; j < 4; j++) {
        ((unsigned short*)&a[kc])[j]     = f2bf(lo[j]);
        ((unsigned short*)&a[kc])[4 + j] = f2bf(hi[j]);
      }
    }
  } else {
    const float* Xa = (const float*)X0v;   // mu (t=0)
    const float* Xb = (const float*)X1v;   // mu (t=1)
#pragma unroll
    for (int kc = 0; kc < 4; kc++) {
      f32x4 lo = *(const f32x4*)(Xa + arow + kc * 32);
      f32x4 hi = *(const f32x4*)(Xa + arow + kc * 32 + 4);
      if (t) {
        f32x4 lo1 = *(const f32x4*)(Xb + arow + kc * 32);
        f32x4 hi1 = *(const f32x4*)(Xb + arow + kc * 32 + 4);
        lo = lo * 0.4f + lo1 * 0.2f;
        hi = hi * 0.4f + hi1 * 0.2f;
      }
#pragma unroll
      for (int j = 0; j < 4; j++) {
        ((unsigned short*)&a[kc])[j]     = f2bf(fmaxf(lo[j], 0.f));
        ((unsigned short*)&a[kc])[4 + j] = f2bf(fmaxf(hi[j], 0.f));
      }
    }
  }

  float sip[4] = {0.f, 0.f, 0.f, 0.f}, sjp[4] = {0.f, 0.f, 0.f, 0.f};
#pragma unroll
  for (int nt = 0; nt < M / 16; nt++) {
    f32x4 acc = {0.f, 0.f, 0.f, 0.f};
    size_t brow = (size_t)(nt * 16 + m16) * K_DIM + quad * 8;
#pragma unroll
    for (int kc = 0; kc < 4; kc++) {
      bf16x8 b = *(const bf16x8*)(Wt + brow + kc * 32);
      acc = __builtin_amdgcn_mfma_f32_16x16x32_bf16(a[kc], b, acc, 0, 0, 0);
    }
    int col = nt * 16 + m16;
    float aA = att[col], aB = att[M + col];
#pragma unroll
    for (int r = 0; r < 4; r++) {
      int row = wave * 16 + quad * 4 + r;
      // hardware fp8 (OCP e4m3) convert — avoids software __hip_fp8 ctor path
      int pk = __builtin_amdgcn_cvt_pk_fp8_f32(acc[r], acc[r], 0, false);
      Hf8[(size_t)row * M + col] = (unsigned char)pk;
      sip[r] += acc[r] * aA;
      sjp[r] += acc[r] * aB;
    }
  }
#pragma unroll
  for (int o = 1; o < 16; o <<= 1) {
#pragma unroll
    for (int r = 0; r < 4; r++) {
      sip[r] += __shfl_xor(sip[r], o);
      sjp[r] += __shfl_xor(sjp[r], o);
    }
  }
  if (m16 == 0) {
#pragma unroll
    for (int r = 0; r < 4; r++) {
      int row = wave * 16 + quad * 4 + r;
      s_i[row] = sip[r];
      s_j[row] = sjp[r];
    }
  }
}

// ---------------- edge-parallel alpha precompute + skl partials ----------------
// Per CSR position: p = clip(sigmoid(leaky(si[dst]+sj[src]))), w = p/deg[dst].
// Writes packed 4B {u16 src | bf16 w} (bf16 w: 0.4% rel err, << fp8-H error).
__global__ __launch_bounds__(256) void edge_kernel(const unsigned int* __restrict__ csr_0,
                                                   const unsigned int* __restrict__ csr_1,
                                                   const float* __restrict__ rn0, const float* __restrict__ rn1,
                                                   const float* __restrict__ si0, const float* __restrict__ si1,
                                                   const float* __restrict__ sj0, const float* __restrict__ sj1,
                                                   unsigned int* __restrict__ iw0, unsigned int* __restrict__ iw1,
                                                   float* __restrict__ epart,  // [2*EBLK]
                                                   int e) {
  int t = blockIdx.y;
  const unsigned int* csr = t ? csr_1 : csr_0;
  const float* rn = t ? rn1 : rn0;
  const float* s_i = t ? si1 : si0;
  const float* s_j = t ? sj1 : sj0;
  unsigned int* iw = t ? iw1 : iw0;

  const float q   = 1.0f / (1.0f + __expf(-(1.0f / 15.0f)));
  const float lq  = __logf(q);
  const float l1q = __logf(1.0f - q);

  __shared__ float red[4];
  float skl = 0.f;
  int p0 = (blockIdx.x * 256 + threadIdx.x) * 2;
#pragma unroll
  for (int u = 0; u < 2; u++) {
    int p = p0 + u;
    if (p < e) {
      unsigned int sd = csr[p];
      int s = (int)(sd & 0xffffu);
      int dd = (int)(sd >> 16);
      float lg = s_i[dd] + s_j[s];
      lg = lg > 0.f ? lg : 0.2f * lg;                 // leaky_relu
      float pv = 1.0f / (1.0f + __expf(-lg));        // sigmoid
      pv = fminf(fmaxf(pv, 0.01f), 0.99f);           // clip
      skl += pv * (__logf(pv) - lq) + (1.0f - pv) * (__logf(1.0f - pv) - l1q);
      float w = pv * rn[dd];                          // fold 1/deg into alpha
      iw[p] = (unsigned int)s | ((unsigned int)f2bf(w) << 16);
    }
  }
  int lane = threadIdx.x & 63, wid = threadIdx.x >> 6;
#pragma unroll
  for (int o = 32; o > 0; o >>= 1) skl += __shfl_xor(skl, o);
  if (lane == 0) red[wid] = skl;
  __syncthreads();
  if (threadIdx.x == 0) epart[t * EBLK + blockIdx.x] = red[0] + red[1] + red[2] + red[3];
}

// ---------------- per-node gather, CHANNEL-SPLIT for L2 residency ----------------
// Grid (ABLK, 4): y -> (t = y>>1, q = y&1). Each phase gathers only the q-half of
// each H row (128B / 64B), so the random working set (3.84 / 1.92 MB) fits the 4MiB
// per-XCD L2 -> random reads hit L2 after the compulsory fill. q=0 = mu half
// (writes mu + ixz-mu); q=1 = std half (softplus ixz only).
// R5-proven codegen: plain arrays, literal indices, no pointer-param lambdas.
template<int M>  // M = 2C
__global__ __launch_bounds__(256) void aggr_kernel(const unsigned char* __restrict__ H0,
                                                   const unsigned char* __restrict__ H1,
                                                   const unsigned int* __restrict__ iw0,
                                                   const unsigned int* __restrict__ iw1,
                                                   const int* __restrict__ off0, const int* __restrict__ off1,
                                                   const int* __restrict__ deg0, const int* __restrict__ deg1,
                                                   const float* __restrict__ bias,
                                                   float* __restrict__ mu0, float* __restrict__ mu1,
                                                   float* __restrict__ apart,  // [4*ABLK] ixz partials
                                                   int n) {
  constexpr int C = M / 2;
  constexpr int HB = M / 2;                    // bytes per row-half: 128 / 64
  constexpr int LPR = HB / 8;                  // lanes per half-row: 16 / 8
  constexpr int L2LPR = (M == 256) ? 4 : 3;
  constexpr int EPL = 64 / LPR;                // edges per load instr: 4 / 8
  constexpr int NL = 4;                        // loads per chunk
  constexpr int U = NL * EPL;                  // edges per chunk: 16 / 32

  int y = blockIdx.y;
  int t = y >> 1, q = y & 1;
  const unsigned char* Hf8 = t ? H1 : H0;
  const unsigned int* iw = t ? iw1 : iw0;
  const int* off = t ? off1 : off0;
  const int* deg = t ? deg1 : deg0;
  float* mu = t ? mu1 : mu0;

  __shared__ float red_i[4];
  int wid = threadIdx.x >> 6, lane = threadIdx.x & 63;
  int wave = blockIdx.x * 4 + wid;
  float ixz = 0.f;

  if (wave < n) {
    int d     = __builtin_amdgcn_readfirstlane(deg[wave]);
    int start = __builtin_amdgcn_readfirstlane(off[wave]);
    const unsigned int* iwp = iw + start;
    int sub = lane & (LPR - 1);
    int g   = lane >> L2LPR;                   // which edge within a load instr
    const unsigned char* hbase = Hf8 + q * HB + sub * 8;   // 8 fp8 channels per lane

    f32x2 acc[4];
#pragma unroll
    for (int k = 0; k < 4; k++) acc[k] = {0.f, 0.f};

    for (int e0 = 0; e0 < d; e0 += U) {
      // NL independent 4B iw loads (broadcast within LPR-lane groups)
      unsigned int iwl[NL];
#pragma unroll
      for (int l = 0; l < NL; l++) {
        int e = e0 + l * EPL + g;
        iwl[l] = iwp[e < d ? e : d - 1];       // clamped, always-valid
      }
      // NL independent 8B half-row gathers (L2-resident region)
      u32x2 hv[NL];
#pragma unroll
      for (int l = 0; l < NL; l++)
        hv[l] = *(const u32x2*)(hbase + (size_t)(iwl[l] & 0xffffu) * M);
      // packed fp8 -> f32 decode + pk-FMA (w=0 for clamped tail edges)
#pragma unroll
      for (int l = 0; l < NL; l++) {
        int e = e0 + l * EPL + g;
        float wf = (e < d) ? __uint_as_float(iwl[l] & 0xffff0000u) : 0.f;
        f32x2 wv = {wf, wf};
        f32x2 d0 = __builtin_amdgcn_cvt_pk_f32_fp8((int)hv[l][0], false);
        f32x2 d1 = __builtin_amdgcn_cvt_pk_f32_fp8((int)hv[l][0], true);
        f32x2 d2 = __builtin_amdgcn_cvt_pk_f32_fp8((int)hv[l][1], false);
        f32x2 d3 = __builtin_amdgcn_cvt_pk_f32_fp8((int)hv[l][1], true);
        acc[0] = d0 * wv + acc[0];
        acc[1] = d1 * wv + acc[1];
        acc[2] = d2 * wv + acc[2];
        acc[3] = d3 * wv + acc[3];
      }
    }

    // combine lane-groups (same channels, different edges)
#pragma unroll
    for (int o = LPR; o < 64; o <<= 1) {
#pragma unroll
      for (int j = 0; j < 4; j++) {
        acc[j][0] += __shfl_xor(acc[j][0], o);
        acc[j][1] += __shfl_xor(acc[j][1], o);
      }
    }

    if (lane < LPR) {
      int ch0 = q * HB + sub * 8;              // channel index (1B per channel)
      if (q == 0) {                            // mu half: ch0 = sub*8 < C
        f32x4 mv[2];
#pragma unroll
        for (int j = 0; j < 4; j++) {
          float a0 = acc[j][0] + bias[ch0 + 2 * j];
          float a1 = acc[j][1] + bias[ch0 + 2 * j + 1];
          ixz += 0.5f * (a0 * a0 + a1 * a1) - 1.0f;
          mv[j >> 1][(j & 1) * 2]     = a0;
          mv[j >> 1][(j & 1) * 2 + 1] = a1;
        }
        *(f32x4*)(mu + (size_t)wave * C + ch0)     = mv[0];
        *(f32x4*)(mu + (size_t)wave * C + ch0 + 4) = mv[1];
      } else {                                 // std half: softplus ixz
#pragma unroll
        for (int j = 0; j < 4; j++) {
#pragma unroll
          for (int h = 0; h < 2; h++) {
            float a = acc[j][h] + bias[ch0 + 2 * j + h];
            float sp = (a > 20.f) ? a : log1pf(__expf(a));  // softplus
            sp += 1e-10f;
            ixz += -__logf(sp) + 0.5f * sp * sp;
          }
        }
      }
    }
  }
#pragma unroll
  for (int o = 32; o > 0; o >>= 1) ixz += __shfl_xor(ixz, o);
  if (lane == 0) red_i[wid] = ixz;
  __syncthreads();
  if (threadIdx.x == 0)
    apart[y * ABLK + blockIdx.x] = red_i[0] + red_i[1] + red_i[2] + red_i[3];
}

// ---------------- layer-2 temporal fusion -> final output (fp32) ----------------
__global__ void fuse2_kernel(const float* __restrict__ mu0, const float* __restrict__ mu1,
                             float* __restrict__ out, int n) {
  int i = blockIdx.x * blockDim.x + threadIdx.x;
  if (i < n) {
    float m0 = mu0[i], m1 = mu1[i];
    out[i] = m0;
    out[n + i] = 0.4f * m0 + 0.2f * m1;
  }
}

// ---------------- final reduction of per-block partials -> scalars ----------------
__global__ __launch_bounds__(1024) void reduce_kernel(const float* __restrict__ a1,
                                                      const float* __restrict__ a2,
                                                      const float* __restrict__ e1,
                                                      const float* __restrict__ e2,
                                                      float* __restrict__ out2) {
  __shared__ float ri[16], rs[16];
  float ixz = 0.f, skl = 0.f;
  for (int i = threadIdx.x; i < 4 * ABLK; i += 1024) ixz += a1[i] + a2[i];
  for (int i = threadIdx.x; i < 2 * EBLK; i += 1024) skl += e1[i] + e2[i];
  int lane = threadIdx.x & 63, wid = threadIdx.x >> 6;
#pragma unroll
  for (int o = 32; o > 0; o >>= 1) {
    ixz += __shfl_xor(ixz, o);
    skl += __shfl_xor(skl, o);
  }
  if (lane == 0) { ri[wid] = ixz; rs[wid] = skl; }
  __syncthreads();
  if (threadIdx.x == 0) {
    float si = 0.f, ss = 0.f;
    for (int w = 0; w < 16; w++) { si += ri[w]; ss += rs[w]; }
    out2[0] = si / (4.0f * (float)N_NODES);
    out2[1] = ss / (4.0f * (float)N_EDGES);
  }
}

extern "C" void kernel_launch(void* const* d_in, const int* in_sizes, int n_in,
                              void* d_out, int out_size, void* d_ws, size_t ws_size,
                              hipStream_t stream) {
  const float* x_all = (const float*)d_in[0];
  const int* ei      = (const int*)d_in[1];
  const float* W1    = (const float*)d_in[2];
  const float* att1  = (const float*)d_in[3];
  const float* b1    = (const float*)d_in[4];
  const float* W2    = (const float*)d_in[5];
  const float* att2  = (const float*)d_in[6];
  const float* b2    = (const float*)d_in[7];
  float* out         = (float*)d_out;

  char* ws = (char*)d_ws;
  size_t off = 0;
  auto alloc = [&](size_t bytes) {
    char* p = ws + off;
    off = (off + bytes + 255) & ~(size_t)255;
    return p;
  };
  unsigned short* wt1  = (unsigned short*)alloc(256 * 128 * sizeof(short));
  unsigned short* wt2  = (unsigned short*)alloc(128 * 128 * sizeof(short));
  unsigned char* hf8_0 = (unsigned char*)alloc((size_t)N_NODES * 256);
  unsigned char* hf8_1 = (unsigned char*)alloc((size_t)N_NODES * 256);
  float* si0   = (float*)alloc(N_NODES * sizeof(float));
  float* si1   = (float*)alloc(N_NODES * sizeof(float));
  float* sj0   = (float*)alloc(N_NODES * sizeof(float));
  float* sj1   = (float*)alloc(N_NODES * sizeof(float));
  float* mu1_0 = (float*)alloc((size_t)N_NODES * 128 * sizeof(float));
  float* mu1_1 = (float*)alloc((size_t)N_NODES * 128 * sizeof(float));
  // mu2 buffers alias mu1_0's region: gemm<128> reads mu1 BEFORE aggr<128> writes mu2
  // (stream-ordered), and fuse2 reads mu2 afterwards.
  float* mu2_0 = mu1_0;
  float* mu2_1 = mu1_0 + (size_t)N_NODES * 64;
  unsigned int* iwp[2] = {(unsigned int*)alloc((size_t)N_EDGES * 4),
                          (unsigned int*)alloc((size_t)N_EDGES * 4)};
  int* degp[2]  = {(int*)alloc(N_NODES * 4), (int*)alloc(N_NODES * 4)};
  int* offp[2]  = {(int*)alloc(N_NODES * 4), (int*)alloc(N_NODES * 4)};
  int* curp[2]  = {(int*)alloc(N_NODES * 4), (int*)alloc(N_NODES * 4)};
  float* rnp[2] = {(float*)alloc(N_NODES * 4), (float*)alloc(N_NODES * 4)};
  unsigned int* csrp[2] = {(unsigned int*)alloc((size_t)N_EDGES * 4),
                           (unsigned int*)alloc((size_t)N_EDGES * 4)};
  float* apart1 = (float*)alloc(4 * ABLK * sizeof(float));
  float* apart2 = (float*)alloc(4 * ABLK * sizeof(float));
  float* epart1 = (float*)alloc(2 * EBLK * sizeof(float));
  float* epart2 = (float*)alloc(2 * EBLK * sizeof(float));

  hipMemsetAsync(degp[0], 0, N_NODES * 4, stream);
  hipMemsetAsync(degp[1], 0, N_NODES * 4, stream);

  transpose_w_kernel<<<192, 256, 0, stream>>>(W1, wt1, W2, wt2);

  deg_kernel<<<(2 * N_EDGES + 255) / 256, 256, 0, stream>>>(ei, degp[0], degp[1], N_EDGES);
  scan_kernel<<<2, 1024, 0, stream>>>(degp[0], offp[0], curp[0], rnp[0],
                                      degp[1], offp[1], curp[1], rnp[1], N_NODES);
  scatter_kernel<<<(2 * N_EDGES + 255) / 256, 256, 0, stream>>>(ei, curp[0], curp[1],
                                                                csrp[0], csrp[1], N_EDGES);

  dim3 ggrid(469, 2), egrid(EBLK, 2), agrid(ABLK, 4);

  // ---- layer 1 (C = 128, M = 256) ----
  const float* x0 = x_all;
  const float* x1 = x_all + (size_t)N_NODES * K_DIM;
  gemm_kernel<256, 0><<<ggrid, 256, 0, stream>>>(x0, x1, (const short*)wt1, hf8_0, hf8_1,
                                                 att1, si0, si1, sj0, sj1, N_NODES);
  edge_kernel<<<egrid, 256, 0, stream>>>(csrp[0], csrp[1], rnp[0], rnp[1],
                                         si0, si1, sj0, sj1, iwp[0], iwp[1], epart1, N_EDGES);
  aggr_kernel<256><<<agrid, 256, 0, stream>>>(hf8_0, hf8_1, iwp[0], iwp[1], offp[0], offp[1],
                                              degp[0], degp[1], b1, mu1_0, mu1_1, apart1, N_NODES);

  // ---- layer 2 (C = 64, M = 128): A-fragment fused from mu1 inline ----
  gemm_kernel<128, 1><<<ggrid, 256, 0, stream>>>(mu1_0, mu1_1, (const short*)wt2, hf8_0, hf8_1,
                                                 att2, si0, si1, sj0, sj1, N_NODES);
  edge_kernel<<<egrid, 256, 0, stream>>>(csrp[0], csrp[1], rnp[0], rnp[1],
                                         si0, si1, sj0, sj1, iwp[0], iwp[1], epart2, N_EDGES);
  aggr_kernel<128><<<agrid, 256, 0, stream>>>(hf8_0, hf8_1, iwp[0], iwp[1], offp[0], offp[1],
                                              degp[0], degp[1], b2, mu2_0, mu2_1, apart2, N_NODES);
  fuse2_kernel<<<(N_NODES * 64 + 255) / 256, 256, 0, stream>>>(mu2_0, mu2_1, out, N_NODES * 64);
  reduce_kernel<<<1, 1024, 0, stream>>>(apart1, apart2, epart1, epart2, out + (size_t)2 * N_NODES * 64);
}

// Round 8
// 603.185 us; speedup vs baseline: 2.4880x; 1.0552x over previous
//
#include <hip/hip_runtime.h>
#include <hip/hip_bf16.h>

#define N_NODES 30000
#define N_EDGES 510000
#define K_DIM   128
#define ABLK    7500   // aggr node-blocks per snapshot (4 nodes/block)

typedef short bf16x8 __attribute__((ext_vector_type(8)));
typedef float f32x4  __attribute__((ext_vector_type(4)));
typedef float f32x2  __attribute__((ext_vector_type(2)));
typedef unsigned int u32x2 __attribute__((ext_vector_type(2)));

__device__ __forceinline__ unsigned short f2bf(float f) {
  __hip_bfloat16 h = __float2bfloat16(f);
  return *(unsigned short*)&h;
}

// ---------------- W transposes (K x M fp32 -> M x K bf16) + in-degree, one kernel ----------------
__global__ void prep_kernel(const float* __restrict__ W1, unsigned short* __restrict__ Wt1,
                            const float* __restrict__ W2, unsigned short* __restrict__ Wt2,
                            const int* __restrict__ ei, int* __restrict__ deg0,
                            int* __restrict__ deg1, int e) {
  int i = blockIdx.x * blockDim.x + threadIdx.x;
  if (i < 128 * 256) {
    int k = i >> 8, m = i & 255;
    Wt1[m * 128 + k] = f2bf(W1[i]);
  } else if (i < 128 * 256 + 128 * 128) {
    int j = i - 128 * 256;
    int k = j >> 7, m = j & 127;
    Wt2[m * 128 + k] = f2bf(W2[j]);
  }
  if (i < 2 * e) {
    int t = i >= e ? 1 : 0;
    int j = i - t * e;
    int d = ei[(size_t)t * 2 * e + e + j];
    atomicAdd(&(t ? deg1 : deg0)[d], 1);
  }
}

// ---------------- exclusive scan (3-phase) + 1/deg, one block per snapshot ----------------
__global__ __launch_bounds__(1024) void scan_kernel(const int* __restrict__ deg0, int* __restrict__ off0,
                                                    int* __restrict__ cur0, float* __restrict__ rn0,
                                                    const int* __restrict__ deg1, int* __restrict__ off1,
                                                    int* __restrict__ cur1, float* __restrict__ rn1,
                                                    int n) {
  const int* deg = blockIdx.x ? deg1 : deg0;
  int* off = blockIdx.x ? off1 : off0;
  int* cur = blockIdx.x ? cur1 : cur0;
  float* rn = blockIdx.x ? rn1 : rn0;
  const int CHUNK = 30;  // 1024*30 >= 30000
  __shared__ int wsum[16];
  int tid = threadIdx.x;
  int base = tid * CHUNK;
  int sum = 0;
  for (int i = 0; i < CHUNK; i++)
    if (base + i < n) sum += deg[base + i];
  int lane = tid & 63, wid = tid >> 6;
  int incl = sum;
#pragma unroll
  for (int o = 1; o < 64; o <<= 1) {
    int v = __shfl_up(incl, o);
    if (lane >= o) incl += v;
  }
  if (lane == 63) wsum[wid] = incl;
  __syncthreads();
  if (tid == 0) {
    int run = 0;
    for (int w = 0; w < 16; w++) { int v = wsum[w]; wsum[w] = run; run += v; }
  }
  __syncthreads();
  int run = incl - sum + wsum[wid];
  for (int i = 0; i < CHUNK; i++) {
    if (base + i < n) {
      int dg = deg[base + i];
      off[base + i] = run;
      cur[base + i] = run;
      rn[base + i] = 1.0f / (float)dg;   // deg >= 1 (self-loop)
      run += dg;
    }
  }
}

// ---------------- scatter edges into dst-major CSR packed {src|dst<<16} ----------------
// src,dst < 30000 < 2^15, so u16 packing is exact.
__global__ void scatter_kernel(const int* __restrict__ ei,
                               int* __restrict__ cur0, int* __restrict__ cur1,
                               unsigned int* __restrict__ csr0, unsigned int* __restrict__ csr1, int e) {
  int i = blockIdx.x * blockDim.x + threadIdx.x;
  if (i < 2 * e) {
    int t = i >= e ? 1 : 0;
    int j = i - t * e;
    int s = ei[(size_t)t * 2 * e + j];
    int d = ei[(size_t)t * 2 * e + e + j];
    int* cur = t ? cur1 : cur0;
    unsigned int* csr = t ? csr1 : csr0;
    int p = atomicAdd(&cur[d], 1);
    csr[p] = (unsigned int)s | ((unsigned int)d << 16);
  }
}

// ---------------- fused GEMM + fp8-H write + per-node attention scores (both t) ----------------
// MODE 0: raw f32 input rows (layer 1).
// MODE 1: A-fragment built inline from layer-1 mu pair: t=0 relu(mu0); t=1 relu(.4mu0+.2mu1).
template<int M, int MODE>
__global__ __launch_bounds__(256) void gemm_kernel(const void* __restrict__ X0v,
                                                   const void* __restrict__ X1v,
                                                   const short* __restrict__ Wt,
                                                   unsigned char* __restrict__ H0,
                                                   unsigned char* __restrict__ H1,
                                                   const float* __restrict__ att,
                                                   float* __restrict__ si0, float* __restrict__ si1,
                                                   float* __restrict__ sj0, float* __restrict__ sj1,
                                                   int nrows) {
  int t = blockIdx.y;
  unsigned char* Hf8 = t ? H1 : H0;
  float* s_i = t ? si1 : si0;
  float* s_j = t ? sj1 : sj0;

  int wave = blockIdx.x * 4 + (threadIdx.x >> 6);
  int lane = threadIdx.x & 63;
  if (wave * 16 >= nrows) return;
  int m16 = lane & 15, quad = lane >> 4;

  bf16x8 a[4];
  size_t arow = (size_t)(wave * 16 + m16) * K_DIM + quad * 8;
  if constexpr (MODE == 0) {
    const float* X = (const float*)(t ? X1v : X0v);
#pragma unroll
    for (int kc = 0; kc < 4; kc++) {
      f32x4 lo = *(const f32x4*)(X + arow + kc * 32);
      f32x4 hi = *(const f32x4*)(X + arow + kc * 32 + 4);
#pragma unroll
      for (int j = 0; j < 4; j++) {
        ((unsigned short*)&a[kc])[j]     = f2bf(lo[j]);
        ((unsigned short*)&a[kc])[4 + j] = f2bf(hi[j]);
      }
    }
  } else {
    const float* Xa = (const float*)X0v;   // mu (t=0)
    const float* Xb = (const float*)X1v;   // mu (t=1)
#pragma unroll
    for (int kc = 0; kc < 4; kc++) {
      f32x4 lo = *(const f32x4*)(Xa + arow + kc * 32);
      f32x4 hi = *(const f32x4*)(Xa + arow + kc * 32 + 4);
      if (t) {
        f32x4 lo1 = *(const f32x4*)(Xb + arow + kc * 32);
        f32x4 hi1 = *(const f32x4*)(Xb + arow + kc * 32 + 4);
        lo = lo * 0.4f + lo1 * 0.2f;
        hi = hi * 0.4f + hi1 * 0.2f;
      }
#pragma unroll
      for (int j = 0; j < 4; j++) {
        ((unsigned short*)&a[kc])[j]     = f2bf(fmaxf(lo[j], 0.f));
        ((unsigned short*)&a[kc])[4 + j] = f2bf(fmaxf(hi[j], 0.f));
      }
    }
  }

  float sip[4] = {0.f, 0.f, 0.f, 0.f}, sjp[4] = {0.f, 0.f, 0.f, 0.f};
#pragma unroll
  for (int nt = 0; nt < M / 16; nt++) {
    f32x4 acc = {0.f, 0.f, 0.f, 0.f};
    size_t brow = (size_t)(nt * 16 + m16) * K_DIM + quad * 8;
#pragma unroll
    for (int kc = 0; kc < 4; kc++) {
      bf16x8 b = *(const bf16x8*)(Wt + brow + kc * 32);
      acc = __builtin_amdgcn_mfma_f32_16x16x32_bf16(a[kc], b, acc, 0, 0, 0);
    }
    int col = nt * 16 + m16;
    float aA = att[col], aB = att[M + col];
#pragma unroll
    for (int r = 0; r < 4; r++) {
      int row = wave * 16 + quad * 4 + r;
      int pk = __builtin_amdgcn_cvt_pk_fp8_f32(acc[r], acc[r], 0, false);
      Hf8[(size_t)row * M + col] = (unsigned char)pk;
      sip[r] += acc[r] * aA;
      sjp[r] += acc[r] * aB;
    }
  }
#pragma unroll
  for (int o = 1; o < 16; o <<= 1) {
#pragma unroll
    for (int r = 0; r < 4; r++) {
      sip[r] += __shfl_xor(sip[r], o);
      sjp[r] += __shfl_xor(sjp[r], o);
    }
  }
  if (m16 == 0) {
#pragma unroll
    for (int r = 0; r < 4; r++) {
      int row = wave * 16 + quad * 4 + r;
      s_i[row] = sip[r];
      s_j[row] = sjp[r];
    }
  }
}

// ---------------- fused per-node aggregation: inline edge-logic + R3 gather ----------------
// One wave per node. Per 64-edge metadata phase: each lane computes one edge's
// {src, w=p/deg} (s_j gather into hot 120KB table + sigmoid chain) and its skl term.
// The gather loop pulls {src,w} via __shfl (register-only). Then R3-proven body:
// NL=4 independent 8B row gathers per chunk, packed fp8 decode + pk-FMA.
template<int M>  // M = 2C
__global__ __launch_bounds__(256) void aggr_kernel(const unsigned char* __restrict__ H0,
                                                   const unsigned char* __restrict__ H1,
                                                   const unsigned int* __restrict__ csr0,
                                                   const unsigned int* __restrict__ csr1,
                                                   const int* __restrict__ off0, const int* __restrict__ off1,
                                                   const int* __restrict__ deg0, const int* __restrict__ deg1,
                                                   const float* __restrict__ rn0, const float* __restrict__ rn1,
                                                   const float* __restrict__ si0, const float* __restrict__ si1,
                                                   const float* __restrict__ sj0, const float* __restrict__ sj1,
                                                   const float* __restrict__ bias,
                                                   float* __restrict__ mu0, float* __restrict__ mu1,
                                                   f32x2* __restrict__ part,  // [2*ABLK] {ixz, skl}
                                                   int n) {
  constexpr int C = M / 2;
  constexpr int LPR = M / 8;                   // lanes per row (8B per lane): 32 / 16
  constexpr int L2LPR = (M == 256) ? 5 : 4;
  constexpr int EPL = 64 / LPR;                // edges per load instr: 2 / 4
  constexpr int NL = 4;                        // loads per chunk
  constexpr int U = NL * EPL;                  // edges per chunk: 8 / 16

  int t = blockIdx.y;
  const unsigned char* Hf8 = t ? H1 : H0;
  const unsigned int* csr = t ? csr1 : csr0;
  const int* off = t ? off1 : off0;
  const int* deg = t ? deg1 : deg0;
  const float* rn = t ? rn1 : rn0;
  const float* s_i = t ? si1 : si0;
  const float* s_j = t ? sj1 : sj0;
  float* mu = t ? mu1 : mu0;

  __shared__ f32x2 red[4];
  int wid = threadIdx.x >> 6, lane = threadIdx.x & 63;
  int wave = blockIdx.x * 4 + wid;
  float ixz = 0.f, skl = 0.f;

  if (wave < n) {
    int d     = __builtin_amdgcn_readfirstlane(deg[wave]);
    int start = __builtin_amdgcn_readfirstlane(off[wave]);
    float siv = s_i[wave];
    float rnv = rn[wave];
    int sub = lane & (LPR - 1);
    int g   = lane >> L2LPR;                   // which edge within a load instr
    const unsigned char* hbase = Hf8 + sub * 8;  // 8 fp8 channels per lane

    const float qc  = 1.0f / (1.0f + __expf(-(1.0f / 15.0f)));
    const float lq  = __logf(qc);
    const float l1q = __logf(1.0f - qc);

    f32x2 acc[4];
#pragma unroll
    for (int k = 0; k < 4; k++) acc[k] = {0.f, 0.f};

    for (int base = 0; base < d; base += 64) {
      // ---- metadata phase: lanes 0..63 each own one edge ----
      int ee = base + lane;
      unsigned int ce = csr[start + (ee < d ? ee : d - 1)];
      int src = (int)(ce & 0xffffu);
      float sj = s_j[src];
      float lg = siv + sj;
      lg = lg > 0.f ? lg : 0.2f * lg;                 // leaky_relu
      float pv = 1.0f / (1.0f + __expf(-lg));        // sigmoid
      pv = fminf(fmaxf(pv, 0.01f), 0.99f);           // clip
      if (ee < d)
        skl += pv * (__logf(pv) - lq) + (1.0f - pv) * (__logf(1.0f - pv) - l1q);
      float wval = (ee < d) ? pv * rnv : 0.f;        // w=0 kills clamped tail edges

      // ---- gather loop: consume up to 64 edges via register shuffles ----
      int cnt = min(d - base, 64);
      for (int c0 = 0; c0 < cnt; c0 += U) {
        int srcl[NL];
        float wl[NL];
#pragma unroll
        for (int l = 0; l < NL; l++) {
          int idx = c0 + l * EPL + g;                // <= 63 by construction
          srcl[l] = __shfl(src, idx);
          wl[l]   = __shfl(wval, idx);
        }
        u32x2 hv[NL];
#pragma unroll
        for (int l = 0; l < NL; l++)
          hv[l] = *(const u32x2*)(hbase + (size_t)srcl[l] * M);
#pragma unroll
        for (int l = 0; l < NL; l++) {
          f32x2 wv = {wl[l], wl[l]};
          f32x2 d0 = __builtin_amdgcn_cvt_pk_f32_fp8((int)hv[l][0], false);
          f32x2 d1 = __builtin_amdgcn_cvt_pk_f32_fp8((int)hv[l][0], true);
          f32x2 d2 = __builtin_amdgcn_cvt_pk_f32_fp8((int)hv[l][1], false);
          f32x2 d3 = __builtin_amdgcn_cvt_pk_f32_fp8((int)hv[l][1], true);
          acc[0] = d0 * wv + acc[0];
          acc[1] = d1 * wv + acc[1];
          acc[2] = d2 * wv + acc[2];
          acc[3] = d3 * wv + acc[3];
        }
      }
    }

    // combine lane-groups (same channels, different edges)
#pragma unroll
    for (int o = LPR; o < 64; o <<= 1) {
#pragma unroll
      for (int j = 0; j < 4; j++) {
        acc[j][0] += __shfl_xor(acc[j][0], o);
        acc[j][1] += __shfl_xor(acc[j][1], o);
      }
    }

    if (lane < LPR) {
      int ch0 = sub * 8;
      if (ch0 < C) {                           // mu channels
        f32x4 mv[2];
#pragma unroll
        for (int j = 0; j < 4; j++) {
          float a0 = acc[j][0] + bias[ch0 + 2 * j];
          float a1 = acc[j][1] + bias[ch0 + 2 * j + 1];
          ixz += 0.5f * (a0 * a0 + a1 * a1) - 1.0f;
          mv[j >> 1][(j & 1) * 2]     = a0;
          mv[j >> 1][(j & 1) * 2 + 1] = a1;
        }
        *(f32x4*)(mu + (size_t)wave * C + ch0)     = mv[0];
        *(f32x4*)(mu + (size_t)wave * C + ch0 + 4) = mv[1];
      } else {                                 // std channels: softplus ixz
#pragma unroll
        for (int j = 0; j < 4; j++) {
#pragma unroll
          for (int h = 0; h < 2; h++) {
            float a = acc[j][h] + bias[ch0 + 2 * j + h];
            float sp = (a > 20.f) ? a : log1pf(__expf(a));  // softplus
            sp += 1e-10f;
            ixz += -__logf(sp) + 0.5f * sp * sp;
          }
        }
      }
    }
  }
#pragma unroll
  for (int o = 32; o > 0; o >>= 1) {
    ixz += __shfl_xor(ixz, o);
    skl += __shfl_xor(skl, o);
  }
  if (lane == 0) { f32x2 r; r[0] = ixz; r[1] = skl; red[wid] = r; }
  __syncthreads();
  if (threadIdx.x == 0) {
    f32x2 pr = red[0] + red[1] + red[2] + red[3];
    part[t * ABLK + blockIdx.x] = pr;
  }
}

// ---------------- layer-2 temporal fusion -> final output (fp32) ----------------
__global__ void fuse2_kernel(const float* __restrict__ mu0, const float* __restrict__ mu1,
                             float* __restrict__ out, int n) {
  int i = blockIdx.x * blockDim.x + threadIdx.x;
  if (i < n) {
    float m0 = mu0[i], m1 = mu1[i];
    out[i] = m0;
    out[n + i] = 0.4f * m0 + 0.2f * m1;
  }
}

// ---------------- final reduction of per-block partials -> scalars ----------------
__global__ __launch_bounds__(1024) void reduce_kernel(const f32x2* __restrict__ p1,
                                                      const f32x2* __restrict__ p2,
                                                      float* __restrict__ out2) {
  __shared__ float ri[16], rs[16];
  float ixz = 0.f, skl = 0.f;
  for (int i = threadIdx.x; i < 2 * ABLK; i += 1024) {
    f32x2 a = p1[i], b = p2[i];
    ixz += a[0] + b[0];
    skl += a[1] + b[1];
  }
  int lane = threadIdx.x & 63, wid = threadIdx.x >> 6;
#pragma unroll
  for (int o = 32; o > 0; o >>= 1) {
    ixz += __shfl_xor(ixz, o);
    skl += __shfl_xor(skl, o);
  }
  if (lane == 0) { ri[wid] = ixz; rs[wid] = skl; }
  __syncthreads();
  if (threadIdx.x == 0) {
    float si = 0.f, ss = 0.f;
    for (int w = 0; w < 16; w++) { si += ri[w]; ss += rs[w]; }
    out2[0] = si / (4.0f * (float)N_NODES);
    out2[1] = ss / (4.0f * (float)N_EDGES);
  }
}

extern "C" void kernel_launch(void* const* d_in, const int* in_sizes, int n_in,
                              void* d_out, int out_size, void* d_ws, size_t ws_size,
                              hipStream_t stream) {
  const float* x_all = (const float*)d_in[0];
  const int* ei      = (const int*)d_in[1];
  const float* W1    = (const float*)d_in[2];
  const float* att1  = (const float*)d_in[3];
  const float* b1    = (const float*)d_in[4];
  const float* W2    = (const float*)d_in[5];
  const float* att2  = (const float*)d_in[6];
  const float* b2    = (const float*)d_in[7];
  float* out         = (float*)d_out;

  char* ws = (char*)d_ws;
  size_t off = 0;
  auto alloc = [&](size_t bytes) {
    char* p = ws + off;
    off = (off + bytes + 255) & ~(size_t)255;
    return p;
  };
  unsigned short* wt1  = (unsigned short*)alloc(256 * 128 * sizeof(short));
  unsigned short* wt2  = (unsigned short*)alloc(128 * 128 * sizeof(short));
  unsigned char* hf8_0 = (unsigned char*)alloc((size_t)N_NODES * 256);
  unsigned char* hf8_1 = (unsigned char*)alloc((size_t)N_NODES * 256);
  float* si0   = (float*)alloc(N_NODES * sizeof(float));
  float* si1   = (float*)alloc(N_NODES * sizeof(float));
  float* sj0   = (float*)alloc(N_NODES * sizeof(float));
  float* sj1   = (float*)alloc(N_NODES * sizeof(float));
  float* mu1_0 = (float*)alloc((size_t)N_NODES * 128 * sizeof(float));
  float* mu1_1 = (float*)alloc((size_t)N_NODES * 128 * sizeof(float));
  // mu2 buffers alias mu1_0's region: gemm2 reads mu1 BEFORE aggr2 writes mu2
  // (stream-ordered); fuse2 reads mu2 afterwards.
  float* mu2_0 = mu1_0;
  float* mu2_1 = mu1_0 + (size_t)N_NODES * 64;
  // deg arrays contiguous -> single memset
  int* degbase  = (int*)alloc(2 * N_NODES * 4);
  int* degp[2]  = {degbase, degbase + N_NODES};
  int* offp[2]  = {(int*)alloc(N_NODES * 4), (int*)alloc(N_NODES * 4)};
  int* curp[2]  = {(int*)alloc(N_NODES * 4), (int*)alloc(N_NODES * 4)};
  float* rnp[2] = {(float*)alloc(N_NODES * 4), (float*)alloc(N_NODES * 4)};
  unsigned int* csrp[2] = {(unsigned int*)alloc((size_t)N_EDGES * 4),
                           (unsigned int*)alloc((size_t)N_EDGES * 4)};
  f32x2* part1 = (f32x2*)alloc(2 * ABLK * sizeof(f32x2));
  f32x2* part2 = (f32x2*)alloc(2 * ABLK * sizeof(f32x2));

  hipMemsetAsync(degbase, 0, 2 * N_NODES * 4, stream);

  prep_kernel<<<(2 * N_EDGES + 255) / 256, 256, 0, stream>>>(W1, wt1, W2, wt2,
                                                             ei, degp[0], degp[1], N_EDGES);
  scan_kernel<<<2, 1024, 0, stream>>>(degp[0], offp[0], curp[0], rnp[0],
                                      degp[1], offp[1], curp[1], rnp[1], N_NODES);
  scatter_kernel<<<(2 * N_EDGES + 255) / 256, 256, 0, stream>>>(ei, curp[0], curp[1],
                                                                csrp[0], csrp[1], N_EDGES);

  dim3 ggrid(469, 2), agrid(ABLK, 2);

  // ---- layer 1 (C = 128, M = 256) ----
  const float* x0 = x_all;
  const float* x1 = x_all + (size_t)N_NODES * K_DIM;
  gemm_kernel<256, 0><<<ggrid, 256, 0, stream>>>(x0, x1, (const short*)wt1, hf8_0, hf8_1,
                                                 att1, si0, si1, sj0, sj1, N_NODES);
  aggr_kernel<256><<<agrid, 256, 0, stream>>>(hf8_0, hf8_1, csrp[0], csrp[1], offp[0], offp[1],
                                              degp[0], degp[1], rnp[0], rnp[1],
                                              si0, si1, sj0, sj1, b1, mu1_0, mu1_1, part1, N_NODES);

  // ---- layer 2 (C = 64, M = 128): A-fragment fused from mu1 inline ----
  gemm_kernel<128, 1><<<ggrid, 256, 0, stream>>>(mu1_0, mu1_1, (const short*)wt2, hf8_0, hf8_1,
                                                 att2, si0, si1, sj0, sj1, N_NODES);
  aggr_kernel<128><<<agrid, 256, 0, stream>>>(hf8_0, hf8_1, csrp[0], csrp[1], offp[0], offp[1],
                                              degp[0], degp[1], rnp[0], rnp[1],
                                              si0, si1, sj0, sj1, b2, mu2_0, mu2_1, part2, N_NODES);
  fuse2_kernel<<<(N_NODES * 64 + 255) / 256, 256, 0, stream>>>(mu2_0, mu2_1, out, N_NODES * 64);
  reduce_kernel<<<1, 1024, 0, stream>>>(part1, part2, out + (size_t)2 * N_NODES * 64);
}

// Round 9
// 540.012 us; speedup vs baseline: 2.7790x; 1.1170x over previous
//
#include <hip/hip_runtime.h>
#include <hip/hip_bf16.h>

#define N_NODES 30000
#define N_EDGES 510000
#define K_DIM   128
#define ABLK    7500   // aggr node-blocks per snapshot (4 nodes/block)
#define SB      59     // scan blocks per snapshot (59*512 >= 30000)
#define SCHUNK  512    // elements per scan block

typedef short bf16x8 __attribute__((ext_vector_type(8)));
typedef float f32x4  __attribute__((ext_vector_type(4)));
typedef float f32x2  __attribute__((ext_vector_type(2)));
typedef unsigned int u32x2 __attribute__((ext_vector_type(2)));

__device__ __forceinline__ unsigned short f2bf(float f) {
  __hip_bfloat16 h = __float2bfloat16(f);
  return *(unsigned short*)&h;
}

// ---------------- W transposes (K x M fp32 -> M x K bf16) + in-degree, one kernel ----------------
__global__ void prep_kernel(const float* __restrict__ W1, unsigned short* __restrict__ Wt1,
                            const float* __restrict__ W2, unsigned short* __restrict__ Wt2,
                            const int* __restrict__ ei, int* __restrict__ deg0,
                            int* __restrict__ deg1, int e) {
  int i = blockIdx.x * blockDim.x + threadIdx.x;
  if (i < 128 * 256) {
    int k = i >> 8, m = i & 255;
    Wt1[m * 128 + k] = f2bf(W1[i]);
  } else if (i < 128 * 256 + 128 * 128) {
    int j = i - 128 * 256;
    int k = j >> 7, m = j & 127;
    Wt2[m * 128 + k] = f2bf(W2[j]);
  }
  if (i < 2 * e) {
    int t = i >= e ? 1 : 0;
    int j = i - t * e;
    int d = ei[(size_t)t * 2 * e + e + j];
    atomicAdd(&(t ? deg1 : deg0)[d], 1);
  }
}

// ---------------- parallel scan, stage 1: per-block sums + rn = 1/deg ----------------
__global__ __launch_bounds__(256) void bsum_kernel(const int* __restrict__ deg0, const int* __restrict__ deg1,
                                                   float* __restrict__ rn0, float* __restrict__ rn1,
                                                   int* __restrict__ bsums,  // [2*SB]
                                                   int n) {
  int t = blockIdx.y;
  const int* deg = t ? deg1 : deg0;
  float* rn = t ? rn1 : rn0;
  __shared__ int red[4];
  int base = blockIdx.x * SCHUNK;
  int sum = 0;
#pragma unroll
  for (int r = 0; r < 2; r++) {
    int idx = base + r * 256 + threadIdx.x;
    if (idx < n) {
      int d = deg[idx];
      sum += d;
      rn[idx] = 1.0f / (float)d;   // deg >= 1 (self-loop)
    }
  }
  int lane = threadIdx.x & 63, wid = threadIdx.x >> 6;
#pragma unroll
  for (int o = 32; o > 0; o >>= 1) sum += __shfl_xor(sum, o);
  if (lane == 0) red[wid] = sum;
  __syncthreads();
  if (threadIdx.x == 0) bsums[t * SB + blockIdx.x] = red[0] + red[1] + red[2] + red[3];
}

// ---------------- parallel scan, stage 2: exclusive scan of block sums (1 block, 2 waves) ----------------
__global__ __launch_bounds__(128) void bscan_kernel(int* __restrict__ bsums) {
  int wid = threadIdx.x >> 6, lane = threadIdx.x & 63;
  int v = (lane < SB) ? bsums[wid * SB + lane] : 0;
  int incl = v;
#pragma unroll
  for (int o = 1; o < 64; o <<= 1) {
    int u = __shfl_up(incl, o);
    if (lane >= o) incl += u;
  }
  if (lane < SB) bsums[wid * SB + lane] = incl - v;  // exclusive
}

// ---------------- parallel scan, stage 3: local scan + write off/cur ----------------
__global__ __launch_bounds__(256) void wout_kernel(const int* __restrict__ deg0, const int* __restrict__ deg1,
                                                   const int* __restrict__ bsums,
                                                   int* __restrict__ off0, int* __restrict__ cur0,
                                                   int* __restrict__ off1, int* __restrict__ cur1,
                                                   int n) {
  int t = blockIdx.y;
  const int* deg = t ? deg1 : deg0;
  int* off = t ? off1 : off0;
  int* cur = t ? cur1 : cur0;
  __shared__ int lds[SCHUNK];
  __shared__ int wpre[4];
  int base = blockIdx.x * SCHUNK;
#pragma unroll
  for (int r = 0; r < 2; r++) {
    int i = r * 256 + threadIdx.x;
    int idx = base + i;
    lds[i] = (idx < n) ? deg[idx] : 0;
  }
  __syncthreads();
  int lane = threadIdx.x & 63, wid = threadIdx.x >> 6;
  int l0 = lds[2 * threadIdx.x], l1 = lds[2 * threadIdx.x + 1];
  int s = l0 + l1;
  int incl = s;
#pragma unroll
  for (int o = 1; o < 64; o <<= 1) {
    int u = __shfl_up(incl, o);
    if (lane >= o) incl += u;
  }
  if (lane == 63) wpre[wid] = incl;
  __syncthreads();
  int wbase = 0;
  if (wid > 0) wbase = wpre[0];
  if (wid > 1) wbase += wpre[1];
  if (wid > 2) wbase += wpre[2];
  int P = bsums[t * SB + blockIdx.x] + wbase + incl - s;  // exclusive prefix for elem 2*tid
  int e0 = base + 2 * threadIdx.x;
  if (e0 < n)     { off[e0] = P;          cur[e0] = P; }
  if (e0 + 1 < n) { off[e0 + 1] = P + l0; cur[e0 + 1] = P + l0; }
}

// ---------------- scatter edges into dst-major CSR packed {src|dst<<16} ----------------
// src,dst < 30000 < 2^15, so u16 packing is exact.
__global__ void scatter_kernel(const int* __restrict__ ei,
                               int* __restrict__ cur0, int* __restrict__ cur1,
                               unsigned int* __restrict__ csr0, unsigned int* __restrict__ csr1, int e) {
  int i = blockIdx.x * blockDim.x + threadIdx.x;
  if (i < 2 * e) {
    int t = i >= e ? 1 : 0;
    int j = i - t * e;
    int s = ei[(size_t)t * 2 * e + j];
    int d = ei[(size_t)t * 2 * e + e + j];
    int* cur = t ? cur1 : cur0;
    unsigned int* csr = t ? csr1 : csr0;
    int p = atomicAdd(&cur[d], 1);
    csr[p] = (unsigned int)s | ((unsigned int)d << 16);
  }
}

// ---------------- fused GEMM + fp8-H write + per-node attention scores (both t) ----------------
// MODE 0: raw f32 input rows (layer 1).
// MODE 1: A-fragment built inline from layer-1 mu pair: t=0 relu(mu0); t=1 relu(.4mu0+.2mu1).
template<int M, int MODE>
__global__ __launch_bounds__(256) void gemm_kernel(const void* __restrict__ X0v,
                                                   const void* __restrict__ X1v,
                                                   const short* __restrict__ Wt,
                                                   unsigned char* __restrict__ H0,
                                                   unsigned char* __restrict__ H1,
                                                   const float* __restrict__ att,
                                                   float* __restrict__ si0, float* __restrict__ si1,
                                                   float* __restrict__ sj0, float* __restrict__ sj1,
                                                   int nrows) {
  int t = blockIdx.y;
  unsigned char* Hf8 = t ? H1 : H0;
  float* s_i = t ? si1 : si0;
  float* s_j = t ? sj1 : sj0;

  int wave = blockIdx.x * 4 + (threadIdx.x >> 6);
  int lane = threadIdx.x & 63;
  if (wave * 16 >= nrows) return;
  int m16 = lane & 15, quad = lane >> 4;

  bf16x8 a[4];
  size_t arow = (size_t)(wave * 16 + m16) * K_DIM + quad * 8;
  if constexpr (MODE == 0) {
    const float* X = (const float*)(t ? X1v : X0v);
#pragma unroll
    for (int kc = 0; kc < 4; kc++) {
      f32x4 lo = *(const f32x4*)(X + arow + kc * 32);
      f32x4 hi = *(const f32x4*)(X + arow + kc * 32 + 4);
#pragma unroll
      for (int j = 0; j < 4; j++) {
        ((unsigned short*)&a[kc])[j]     = f2bf(lo[j]);
        ((unsigned short*)&a[kc])[4 + j] = f2bf(hi[j]);
      }
    }
  } else {
    const float* Xa = (const float*)X0v;   // mu (t=0)
    const float* Xb = (const float*)X1v;   // mu (t=1)
#pragma unroll
    for (int kc = 0; kc < 4; kc++) {
      f32x4 lo = *(const f32x4*)(Xa + arow + kc * 32);
      f32x4 hi = *(const f32x4*)(Xa + arow + kc * 32 + 4);
      if (t) {
        f32x4 lo1 = *(const f32x4*)(Xb + arow + kc * 32);
        f32x4 hi1 = *(const f32x4*)(Xb + arow + kc * 32 + 4);
        lo = lo * 0.4f + lo1 * 0.2f;
        hi = hi * 0.4f + hi1 * 0.2f;
      }
#pragma unroll
      for (int j = 0; j < 4; j++) {
        ((unsigned short*)&a[kc])[j]     = f2bf(fmaxf(lo[j], 0.f));
        ((unsigned short*)&a[kc])[4 + j] = f2bf(fmaxf(hi[j], 0.f));
      }
    }
  }

  float sip[4] = {0.f, 0.f, 0.f, 0.f}, sjp[4] = {0.f, 0.f, 0.f, 0.f};
#pragma unroll
  for (int nt = 0; nt < M / 16; nt++) {
    f32x4 acc = {0.f, 0.f, 0.f, 0.f};
    size_t brow = (size_t)(nt * 16 + m16) * K_DIM + quad * 8;
#pragma unroll
    for (int kc = 0; kc < 4; kc++) {
      bf16x8 b = *(const bf16x8*)(Wt + brow + kc * 32);
      acc = __builtin_amdgcn_mfma_f32_16x16x32_bf16(a[kc], b, acc, 0, 0, 0);
    }
    int col = nt * 16 + m16;
    float aA = att[col], aB = att[M + col];
#pragma unroll
    for (int r = 0; r < 4; r++) {
      int row = wave * 16 + quad * 4 + r;
      int pk = __builtin_amdgcn_cvt_pk_fp8_f32(acc[r], acc[r], 0, false);
      Hf8[(size_t)row * M + col] = (unsigned char)pk;
      sip[r] += acc[r] * aA;
      sjp[r] += acc[r] * aB;
    }
  }
#pragma unroll
  for (int o = 1; o < 16; o <<= 1) {
#pragma unroll
    for (int r = 0; r < 4; r++) {
      sip[r] += __shfl_xor(sip[r], o);
      sjp[r] += __shfl_xor(sjp[r], o);
    }
  }
  if (m16 == 0) {
#pragma unroll
    for (int r = 0; r < 4; r++) {
      int row = wave * 16 + quad * 4 + r;
      s_i[row] = sip[r];
      s_j[row] = sjp[r];
    }
  }
}

// ---------------- fused per-node aggregation: inline edge-logic + R3 gather ----------------
// One wave per node. Per 64-edge metadata phase: each lane computes one edge's
// {src, w=p/deg} (s_j gather into hot 120KB table + sigmoid chain) and its skl term.
// The gather loop pulls {src,w} via __shfl (register-only). R3-proven body:
// NL=4 independent 8B row gathers per chunk (nontemporal: lines never reused via L1),
// packed fp8 decode + pk-FMA.
template<int M>  // M = 2C
__global__ __launch_bounds__(256) void aggr_kernel(const unsigned char* __restrict__ H0,
                                                   const unsigned char* __restrict__ H1,
                                                   const unsigned int* __restrict__ csr0,
                                                   const unsigned int* __restrict__ csr1,
                                                   const int* __restrict__ off0, const int* __restrict__ off1,
                                                   const int* __restrict__ deg0, const int* __restrict__ deg1,
                                                   const float* __restrict__ rn0, const float* __restrict__ rn1,
                                                   const float* __restrict__ si0, const float* __restrict__ si1,
                                                   const float* __restrict__ sj0, const float* __restrict__ sj1,
                                                   const float* __restrict__ bias,
                                                   float* __restrict__ mu0, float* __restrict__ mu1,
                                                   f32x2* __restrict__ part,  // [2*ABLK] {ixz, skl}
                                                   int n) {
  constexpr int C = M / 2;
  constexpr int LPR = M / 8;                   // lanes per row (8B per lane): 32 / 16
  constexpr int L2LPR = (M == 256) ? 5 : 4;
  constexpr int EPL = 64 / LPR;                // edges per load instr: 2 / 4
  constexpr int NL = 4;                        // loads per chunk
  constexpr int U = NL * EPL;                  // edges per chunk: 8 / 16

  int t = blockIdx.y;
  const unsigned char* Hf8 = t ? H1 : H0;
  const unsigned int* csr = t ? csr1 : csr0;
  const int* off = t ? off1 : off0;
  const int* deg = t ? deg1 : deg0;
  const float* rn = t ? rn1 : rn0;
  const float* s_i = t ? si1 : si0;
  const float* s_j = t ? sj1 : sj0;
  float* mu = t ? mu1 : mu0;

  __shared__ f32x2 red[4];
  int wid = threadIdx.x >> 6, lane = threadIdx.x & 63;
  int wave = blockIdx.x * 4 + wid;
  float ixz = 0.f, skl = 0.f;

  if (wave < n) {
    int d     = __builtin_amdgcn_readfirstlane(deg[wave]);
    int start = __builtin_amdgcn_readfirstlane(off[wave]);
    float siv = s_i[wave];
    float rnv = rn[wave];
    int sub = lane & (LPR - 1);
    int g   = lane >> L2LPR;                   // which edge within a load instr
    const unsigned char* hbase = Hf8 + sub * 8;  // 8 fp8 channels per lane

    const float qc  = 1.0f / (1.0f + __expf(-(1.0f / 15.0f)));
    const float lq  = __logf(qc);
    const float l1q = __logf(1.0f - qc);

    f32x2 acc[4];
#pragma unroll
    for (int k = 0; k < 4; k++) acc[k] = {0.f, 0.f};

    for (int base = 0; base < d; base += 64) {
      // ---- metadata phase: lanes 0..63 each own one edge ----
      int ee = base + lane;
      unsigned int ce = csr[start + (ee < d ? ee : d - 1)];
      int src = (int)(ce & 0xffffu);
      float sj = s_j[src];
      float lg = siv + sj;
      lg = lg > 0.f ? lg : 0.2f * lg;                 // leaky_relu
      float pv = 1.0f / (1.0f + __expf(-lg));        // sigmoid
      pv = fminf(fmaxf(pv, 0.01f), 0.99f);           // clip
      if (ee < d)
        skl += pv * (__logf(pv) - lq) + (1.0f - pv) * (__logf(1.0f - pv) - l1q);
      float wval = (ee < d) ? pv * rnv : 0.f;        // w=0 kills clamped tail edges

      // ---- gather loop: consume up to 64 edges via register shuffles ----
      int cnt = min(d - base, 64);
      for (int c0 = 0; c0 < cnt; c0 += U) {
        int srcl[NL];
        float wl[NL];
#pragma unroll
        for (int l = 0; l < NL; l++) {
          int idx = c0 + l * EPL + g;                // <= 63 by construction
          srcl[l] = __shfl(src, idx);
          wl[l]   = __shfl(wval, idx);
        }
        u32x2 hv[NL];
#pragma unroll
        for (int l = 0; l < NL; l++)
          hv[l] = __builtin_nontemporal_load((const u32x2*)(hbase + (size_t)srcl[l] * M));
#pragma unroll
        for (int l = 0; l < NL; l++) {
          f32x2 wv = {wl[l], wl[l]};
          f32x2 d0 = __builtin_amdgcn_cvt_pk_f32_fp8((int)hv[l][0], false);
          f32x2 d1 = __builtin_amdgcn_cvt_pk_f32_fp8((int)hv[l][0], true);
          f32x2 d2 = __builtin_amdgcn_cvt_pk_f32_fp8((int)hv[l][1], false);
          f32x2 d3 = __builtin_amdgcn_cvt_pk_f32_fp8((int)hv[l][1], true);
          acc[0] = d0 * wv + acc[0];
          acc[1] = d1 * wv + acc[1];
          acc[2] = d2 * wv + acc[2];
          acc[3] = d3 * wv + acc[3];
        }
      }
    }

    // combine lane-groups (same channels, different edges)
#pragma unroll
    for (int o = LPR; o < 64; o <<= 1) {
#pragma unroll
      for (int j = 0; j < 4; j++) {
        acc[j][0] += __shfl_xor(acc[j][0], o);
        acc[j][1] += __shfl_xor(acc[j][1], o);
      }
    }

    if (lane < LPR) {
      int ch0 = sub * 8;
      if (ch0 < C) {                           // mu channels
        f32x4 mv[2];
#pragma unroll
        for (int j = 0; j < 4; j++) {
          float a0 = acc[j][0] + bias[ch0 + 2 * j];
          float a1 = acc[j][1] + bias[ch0 + 2 * j + 1];
          ixz += 0.5f * (a0 * a0 + a1 * a1) - 1.0f;
          mv[j >> 1][(j & 1) * 2]     = a0;
          mv[j >> 1][(j & 1) * 2 + 1] = a1;
        }
        *(f32x4*)(mu + (size_t)wave * C + ch0)     = mv[0];
        *(f32x4*)(mu + (size_t)wave * C + ch0 + 4) = mv[1];
      } else {                                 // std channels: softplus ixz
#pragma unroll
        for (int j = 0; j < 4; j++) {
#pragma unroll
          for (int h = 0; h < 2; h++) {
            float a = acc[j][h] + bias[ch0 + 2 * j + h];
            float sp = (a > 20.f) ? a : log1pf(__expf(a));  // softplus
            sp += 1e-10f;
            ixz += -__logf(sp) + 0.5f * sp * sp;
          }
        }
      }
    }
  }
#pragma unroll
  for (int o = 32; o > 0; o >>= 1) {
    ixz += __shfl_xor(ixz, o);
    skl += __shfl_xor(skl, o);
  }
  if (lane == 0) { f32x2 r; r[0] = ixz; r[1] = skl; red[wid] = r; }
  __syncthreads();
  if (threadIdx.x == 0) {
    f32x2 pr = red[0] + red[1] + red[2] + red[3];
    part[t * ABLK + blockIdx.x] = pr;
  }
}

// ---------------- layer-2 temporal fusion -> final output (fp32) ----------------
__global__ void fuse2_kernel(const float* __restrict__ mu0, const float* __restrict__ mu1,
                             float* __restrict__ out, int n) {
  int i = blockIdx.x * blockDim.x + threadIdx.x;
  if (i < n) {
    float m0 = mu0[i], m1 = mu1[i];
    out[i] = m0;
    out[n + i] = 0.4f * m0 + 0.2f * m1;
  }
}

// ---------------- final reduction of per-block partials -> scalars ----------------
__global__ __launch_bounds__(1024) void reduce_kernel(const f32x2* __restrict__ p1,
                                                      const f32x2* __restrict__ p2,
                                                      float* __restrict__ out2) {
  __shared__ float ri[16], rs[16];
  float ixz = 0.f, skl = 0.f;
  for (int i = threadIdx.x; i < 2 * ABLK; i += 1024) {
    f32x2 a = p1[i], b = p2[i];
    ixz += a[0] + b[0];
    skl += a[1] + b[1];
  }
  int lane = threadIdx.x & 63, wid = threadIdx.x >> 6;
#pragma unroll
  for (int o = 32; o > 0; o >>= 1) {
    ixz += __shfl_xor(ixz, o);
    skl += __shfl_xor(skl, o);
  }
  if (lane == 0) { ri[wid] = ixz; rs[wid] = skl; }
  __syncthreads();
  if (threadIdx.x == 0) {
    float si = 0.f, ss = 0.f;
    for (int w = 0; w < 16; w++) { si += ri[w]; ss += rs[w]; }
    out2[0] = si / (4.0f * (float)N_NODES);
    out2[1] = ss / (4.0f * (float)N_EDGES);
  }
}

extern "C" void kernel_launch(void* const* d_in, const int* in_sizes, int n_in,
                              void* d_out, int out_size, void* d_ws, size_t ws_size,
                              hipStream_t stream) {
  const float* x_all = (const float*)d_in[0];
  const int* ei      = (const int*)d_in[1];
  const float* W1    = (const float*)d_in[2];
  const float* att1  = (const float*)d_in[3];
  const float* b1    = (const float*)d_in[4];
  const float* W2    = (const float*)d_in[5];
  const float* att2  = (const float*)d_in[6];
  const float* b2    = (const float*)d_in[7];
  float* out         = (float*)d_out;

  char* ws = (char*)d_ws;
  size_t off = 0;
  auto alloc = [&](size_t bytes) {
    char* p = ws + off;
    off = (off + bytes + 255) & ~(size_t)255;
    return p;
  };
  unsigned short* wt1  = (unsigned short*)alloc(256 * 128 * sizeof(short));
  unsigned short* wt2  = (unsigned short*)alloc(128 * 128 * sizeof(short));
  unsigned char* hf8_0 = (unsigned char*)alloc((size_t)N_NODES * 256);
  unsigned char* hf8_1 = (unsigned char*)alloc((size_t)N_NODES * 256);
  float* si0   = (float*)alloc(N_NODES * sizeof(float));
  float* si1   = (float*)alloc(N_NODES * sizeof(float));
  float* sj0   = (float*)alloc(N_NODES * sizeof(float));
  float* sj1   = (float*)alloc(N_NODES * sizeof(float));
  float* mu1_0 = (float*)alloc((size_t)N_NODES * 128 * sizeof(float));
  float* mu1_1 = (float*)alloc((size_t)N_NODES * 128 * sizeof(float));
  // mu2 buffers alias mu1_0's region: gemm2 reads mu1 BEFORE aggr2 writes mu2
  // (stream-ordered); fuse2 reads mu2 afterwards.
  float* mu2_0 = mu1_0;
  float* mu2_1 = mu1_0 + (size_t)N_NODES * 64;
  // deg arrays contiguous -> single memset
  int* degbase  = (int*)alloc(2 * N_NODES * 4);
  int* degp[2]  = {degbase, degbase + N_NODES};
  int* offp[2]  = {(int*)alloc(N_NODES * 4), (int*)alloc(N_NODES * 4)};
  int* curp[2]  = {(int*)alloc(N_NODES * 4), (int*)alloc(N_NODES * 4)};
  float* rnp[2] = {(float*)alloc(N_NODES * 4), (float*)alloc(N_NODES * 4)};
  unsigned int* csrp[2] = {(unsigned int*)alloc((size_t)N_EDGES * 4),
                           (unsigned int*)alloc((size_t)N_EDGES * 4)};
  int* bsums   = (int*)alloc(2 * SB * sizeof(int));
  f32x2* part1 = (f32x2*)alloc(2 * ABLK * sizeof(f32x2));
  f32x2* part2 = (f32x2*)alloc(2 * ABLK * sizeof(f32x2));

  hipMemsetAsync(degbase, 0, 2 * N_NODES * 4, stream);

  prep_kernel<<<(2 * N_EDGES + 255) / 256, 256, 0, stream>>>(W1, wt1, W2, wt2,
                                                             ei, degp[0], degp[1], N_EDGES);
  dim3 sgrid(SB, 2);
  bsum_kernel<<<sgrid, 256, 0, stream>>>(degp[0], degp[1], rnp[0], rnp[1], bsums, N_NODES);
  bscan_kernel<<<1, 128, 0, stream>>>(bsums);
  wout_kernel<<<sgrid, 256, 0, stream>>>(degp[0], degp[1], bsums,
                                         offp[0], curp[0], offp[1], curp[1], N_NODES);
  scatter_kernel<<<(2 * N_EDGES + 255) / 256, 256, 0, stream>>>(ei, curp[0], curp[1],
                                                                csrp[0], csrp[1], N_EDGES);

  dim3 ggrid(469, 2), agrid(ABLK, 2);

  // ---- layer 1 (C = 128, M = 256) ----
  const float* x0 = x_all;
  const float* x1 = x_all + (size_t)N_NODES * K_DIM;
  gemm_kernel<256, 0><<<ggrid, 256, 0, stream>>>(x0, x1, (const short*)wt1, hf8_0, hf8_1,
                                                 att1, si0, si1, sj0, sj1, N_NODES);
  aggr_kernel<256><<<agrid, 256, 0, stream>>>(hf8_0, hf8_1, csrp[0], csrp[1], offp[0], offp[1],
                                              degp[0], degp[1], rnp[0], rnp[1],
                                              si0, si1, sj0, sj1, b1, mu1_0, mu1_1, part1, N_NODES);

  // ---- layer 2 (C = 64, M = 128): A-fragment fused from mu1 inline ----
  gemm_kernel<128, 1><<<ggrid, 256, 0, stream>>>(mu1_0, mu1_1, (const short*)wt2, hf8_0, hf8_1,
                                                 att2, si0, si1, sj0, sj1, N_NODES);
  aggr_kernel<128><<<agrid, 256, 0, stream>>>(hf8_0, hf8_1, csrp[0], csrp[1], offp[0], offp[1],
                                              degp[0], degp[1], rnp[0], rnp[1],
                                              si0, si1, sj0, sj1, b2, mu2_0, mu2_1, part2, N_NODES);
  fuse2_kernel<<<(N_NODES * 64 + 255) / 256, 256, 0, stream>>>(mu2_0, mu2_1, out, N_NODES * 64);
  reduce_kernel<<<1, 1024, 0, stream>>>(part1, part2, out + (size_t)2 * N_NODES * 64);
}

// Round 10
// 530.211 us; speedup vs baseline: 2.8304x; 1.0185x over previous
//
#include <hip/hip_runtime.h>
#include <hip/hip_bf16.h>

#define N_NODES 30000
#define N_EDGES 510000
#define K_DIM   128
#define ABLK    7500   // aggr node-blocks per snapshot (4 nodes/block)
#define SB      59     // scan blocks per snapshot (59*512 >= 30000)
#define SCHUNK  512    // elements per scan block

typedef short bf16x8 __attribute__((ext_vector_type(8)));
typedef float f32x4  __attribute__((ext_vector_type(4)));
typedef float f32x2  __attribute__((ext_vector_type(2)));
typedef unsigned int u32x2 __attribute__((ext_vector_type(2)));

__device__ __forceinline__ unsigned short f2bf(float f) {
  __hip_bfloat16 h = __float2bfloat16(f);
  return *(unsigned short*)&h;
}

// ---------------- W transposes (K x M fp32 -> M x K bf16) + in-degree, one kernel ----------------
__global__ void prep_kernel(const float* __restrict__ W1, unsigned short* __restrict__ Wt1,
                            const float* __restrict__ W2, unsigned short* __restrict__ Wt2,
                            const int* __restrict__ ei, int* __restrict__ deg0,
                            int* __restrict__ deg1, int e) {
  int i = blockIdx.x * blockDim.x + threadIdx.x;
  if (i < 128 * 256) {
    int k = i >> 8, m = i & 255;
    Wt1[m * 128 + k] = f2bf(W1[i]);
  } else if (i < 128 * 256 + 128 * 128) {
    int j = i - 128 * 256;
    int k = j >> 7, m = j & 127;
    Wt2[m * 128 + k] = f2bf(W2[j]);
  }
  if (i < 2 * e) {
    int t = i >= e ? 1 : 0;
    int j = i - t * e;
    int d = ei[(size_t)t * 2 * e + e + j];
    atomicAdd(&(t ? deg1 : deg0)[d], 1);
  }
}

// ---------------- parallel scan, stage 1: per-block sums + rn = 1/deg ----------------
__global__ __launch_bounds__(256) void bsum_kernel(const int* __restrict__ deg0, const int* __restrict__ deg1,
                                                   float* __restrict__ rn0, float* __restrict__ rn1,
                                                   int* __restrict__ bsums,  // [2*SB]
                                                   int n) {
  int t = blockIdx.y;
  const int* deg = t ? deg1 : deg0;
  float* rn = t ? rn1 : rn0;
  __shared__ int red[4];
  int base = blockIdx.x * SCHUNK;
  int sum = 0;
#pragma unroll
  for (int r = 0; r < 2; r++) {
    int idx = base + r * 256 + threadIdx.x;
    if (idx < n) {
      int d = deg[idx];
      sum += d;
      rn[idx] = 1.0f / (float)d;   // deg >= 1 (self-loop)
    }
  }
  int lane = threadIdx.x & 63, wid = threadIdx.x >> 6;
#pragma unroll
  for (int o = 32; o > 0; o >>= 1) sum += __shfl_xor(sum, o);
  if (lane == 0) red[wid] = sum;
  __syncthreads();
  if (threadIdx.x == 0) bsums[t * SB + blockIdx.x] = red[0] + red[1] + red[2] + red[3];
}

// ---------------- parallel scan, stage 2: exclusive scan of block sums (1 block, 2 waves) ----------------
__global__ __launch_bounds__(128) void bscan_kernel(int* __restrict__ bsums) {
  int wid = threadIdx.x >> 6, lane = threadIdx.x & 63;
  int v = (lane < SB) ? bsums[wid * SB + lane] : 0;
  int incl = v;
#pragma unroll
  for (int o = 1; o < 64; o <<= 1) {
    int u = __shfl_up(incl, o);
    if (lane >= o) incl += u;
  }
  if (lane < SB) bsums[wid * SB + lane] = incl - v;  // exclusive
}

// ---------------- parallel scan, stage 3: local scan + write off/cur ----------------
__global__ __launch_bounds__(256) void wout_kernel(const int* __restrict__ deg0, const int* __restrict__ deg1,
                                                   const int* __restrict__ bsums,
                                                   int* __restrict__ off0, int* __restrict__ cur0,
                                                   int* __restrict__ off1, int* __restrict__ cur1,
                                                   int n) {
  int t = blockIdx.y;
  const int* deg = t ? deg1 : deg0;
  int* off = t ? off1 : off0;
  int* cur = t ? cur1 : cur0;
  __shared__ int lds[SCHUNK];
  __shared__ int wpre[4];
  int base = blockIdx.x * SCHUNK;
#pragma unroll
  for (int r = 0; r < 2; r++) {
    int i = r * 256 + threadIdx.x;
    int idx = base + i;
    lds[i] = (idx < n) ? deg[idx] : 0;
  }
  __syncthreads();
  int lane = threadIdx.x & 63, wid = threadIdx.x >> 6;
  int l0 = lds[2 * threadIdx.x], l1 = lds[2 * threadIdx.x + 1];
  int s = l0 + l1;
  int incl = s;
#pragma unroll
  for (int o = 1; o < 64; o <<= 1) {
    int u = __shfl_up(incl, o);
    if (lane >= o) incl += u;
  }
  if (lane == 63) wpre[wid] = incl;
  __syncthreads();
  int wbase = 0;
  if (wid > 0) wbase = wpre[0];
  if (wid > 1) wbase += wpre[1];
  if (wid > 2) wbase += wpre[2];
  int P = bsums[t * SB + blockIdx.x] + wbase + incl - s;  // exclusive prefix for elem 2*tid
  int e0 = base + 2 * threadIdx.x;
  if (e0 < n)     { off[e0] = P;          cur[e0] = P; }
  if (e0 + 1 < n) { off[e0 + 1] = P + l0; cur[e0 + 1] = P + l0; }
}

// ---------------- scatter edges into dst-major CSR packed {src|dst<<16} ----------------
// src,dst < 30000 < 2^15, so u16 packing is exact.
__global__ void scatter_kernel(const int* __restrict__ ei,
                               int* __restrict__ cur0, int* __restrict__ cur1,
                               unsigned int* __restrict__ csr0, unsigned int* __restrict__ csr1, int e) {
  int i = blockIdx.x * blockDim.x + threadIdx.x;
  if (i < 2 * e) {
    int t = i >= e ? 1 : 0;
    int j = i - t * e;
    int s = ei[(size_t)t * 2 * e + j];
    int d = ei[(size_t)t * 2 * e + e + j];
    int* cur = t ? cur1 : cur0;
    unsigned int* csr = t ? csr1 : csr0;
    int p = atomicAdd(&cur[d], 1);
    csr[p] = (unsigned int)s | ((unsigned int)d << 16);
  }
}

// ---------------- fused GEMM + fp8-H write + per-node attention scores (both t) ----------------
// MODE 0: raw f32 input rows (layer 1).
// MODE 1: A-fragment built inline from layer-1 mu pair: t=0 relu(mu0); t=1 relu(.4mu0+.2mu1).
template<int M, int MODE>
__global__ __launch_bounds__(256) void gemm_kernel(const void* __restrict__ X0v,
                                                   const void* __restrict__ X1v,
                                                   const short* __restrict__ Wt,
                                                   unsigned char* __restrict__ H0,
                                                   unsigned char* __restrict__ H1,
                                                   const float* __restrict__ att,
                                                   float* __restrict__ si0, float* __restrict__ si1,
                                                   float* __restrict__ sj0, float* __restrict__ sj1,
                                                   int nrows) {
  int t = blockIdx.y;
  unsigned char* Hf8 = t ? H1 : H0;
  float* s_i = t ? si1 : si0;
  float* s_j = t ? sj1 : sj0;

  int wave = blockIdx.x * 4 + (threadIdx.x >> 6);
  int lane = threadIdx.x & 63;
  if (wave * 16 >= nrows) return;
  int m16 = lane & 15, quad = lane >> 4;

  bf16x8 a[4];
  size_t arow = (size_t)(wave * 16 + m16) * K_DIM + quad * 8;
  if constexpr (MODE == 0) {
    const float* X = (const float*)(t ? X1v : X0v);
#pragma unroll
    for (int kc = 0; kc < 4; kc++) {
      f32x4 lo = *(const f32x4*)(X + arow + kc * 32);
      f32x4 hi = *(const f32x4*)(X + arow + kc * 32 + 4);
#pragma unroll
      for (int j = 0; j < 4; j++) {
        ((unsigned short*)&a[kc])[j]     = f2bf(lo[j]);
        ((unsigned short*)&a[kc])[4 + j] = f2bf(hi[j]);
      }
    }
  } else {
    const float* Xa = (const float*)X0v;   // mu (t=0)
    const float* Xb = (const float*)X1v;   // mu (t=1)
#pragma unroll
    for (int kc = 0; kc < 4; kc++) {
      f32x4 lo = *(const f32x4*)(Xa + arow + kc * 32);
      f32x4 hi = *(const f32x4*)(Xa + arow + kc * 32 + 4);
      if (t) {
        f32x4 lo1 = *(const f32x4*)(Xb + arow + kc * 32);
        f32x4 hi1 = *(const f32x4*)(Xb + arow + kc * 32 + 4);
        lo = lo * 0.4f + lo1 * 0.2f;
        hi = hi * 0.4f + hi1 * 0.2f;
      }
#pragma unroll
      for (int j = 0; j < 4; j++) {
        ((unsigned short*)&a[kc])[j]     = f2bf(fmaxf(lo[j], 0.f));
        ((unsigned short*)&a[kc])[4 + j] = f2bf(fmaxf(hi[j], 0.f));
      }
    }
  }

  float sip[4] = {0.f, 0.f, 0.f, 0.f}, sjp[4] = {0.f, 0.f, 0.f, 0.f};
#pragma unroll
  for (int nt = 0; nt < M / 16; nt++) {
    f32x4 acc = {0.f, 0.f, 0.f, 0.f};
    size_t brow = (size_t)(nt * 16 + m16) * K_DIM + quad * 8;
#pragma unroll
    for (int kc = 0; kc < 4; kc++) {
      bf16x8 b = *(const bf16x8*)(Wt + brow + kc * 32);
      acc = __builtin_amdgcn_mfma_f32_16x16x32_bf16(a[kc], b, acc, 0, 0, 0);
    }
    int col = nt * 16 + m16;
    float aA = att[col], aB = att[M + col];
#pragma unroll
    for (int r = 0; r < 4; r++) {
      int row = wave * 16 + quad * 4 + r;
      int pk = __builtin_amdgcn_cvt_pk_fp8_f32(acc[r], acc[r], 0, false);
      Hf8[(size_t)row * M + col] = (unsigned char)pk;
      sip[r] += acc[r] * aA;
      sjp[r] += acc[r] * aB;
    }
  }
#pragma unroll
  for (int o = 1; o < 16; o <<= 1) {
#pragma unroll
    for (int r = 0; r < 4; r++) {
      sip[r] += __shfl_xor(sip[r], o);
      sjp[r] += __shfl_xor(sjp[r], o);
    }
  }
  if (m16 == 0) {
#pragma unroll
    for (int r = 0; r < 4; r++) {
      int row = wave * 16 + quad * 4 + r;
      s_i[row] = sip[r];
      s_j[row] = sjp[r];
    }
  }
}

// ---------------- fused per-node aggregation: inline edge-logic + R3 gather ----------------
// One wave per node. Per 64-edge metadata phase: each lane computes one edge's
// {src, w=p/deg} (s_j gather into hot 120KB table + sigmoid chain) and its skl term.
// The gather loop pulls {src,w} via __shfl (register-only). R3-proven body:
// NL=4 independent 8B row gathers per chunk (plain loads: nontemporal REGRESSED in R9,
// FETCH 87->113MB — nt weakens L2 retention on gfx950), packed fp8 decode + pk-FMA.
template<int M>  // M = 2C
__global__ __launch_bounds__(256) void aggr_kernel(const unsigned char* __restrict__ H0,
                                                   const unsigned char* __restrict__ H1,
                                                   const unsigned int* __restrict__ csr0,
                                                   const unsigned int* __restrict__ csr1,
                                                   const int* __restrict__ off0, const int* __restrict__ off1,
                                                   const int* __restrict__ deg0, const int* __restrict__ deg1,
                                                   const float* __restrict__ rn0, const float* __restrict__ rn1,
                                                   const float* __restrict__ si0, const float* __restrict__ si1,
                                                   const float* __restrict__ sj0, const float* __restrict__ sj1,
                                                   const float* __restrict__ bias,
                                                   float* __restrict__ mu0, float* __restrict__ mu1,
                                                   f32x2* __restrict__ part,  // [2*ABLK] {ixz, skl}
                                                   int n) {
  constexpr int C = M / 2;
  constexpr int LPR = M / 8;                   // lanes per row (8B per lane): 32 / 16
  constexpr int L2LPR = (M == 256) ? 5 : 4;
  constexpr int EPL = 64 / LPR;                // edges per load instr: 2 / 4
  constexpr int NL = 4;                        // loads per chunk
  constexpr int U = NL * EPL;                  // edges per chunk: 8 / 16

  int t = blockIdx.y;
  const unsigned char* Hf8 = t ? H1 : H0;
  const unsigned int* csr = t ? csr1 : csr0;
  const int* off = t ? off1 : off0;
  const int* deg = t ? deg1 : deg0;
  const float* rn = t ? rn1 : rn0;
  const float* s_i = t ? si1 : si0;
  const float* s_j = t ? sj1 : sj0;
  float* mu = t ? mu1 : mu0;

  __shared__ f32x2 red[4];
  int wid = threadIdx.x >> 6, lane = threadIdx.x & 63;
  int wave = blockIdx.x * 4 + wid;
  float ixz = 0.f, skl = 0.f;

  if (wave < n) {
    int d     = __builtin_amdgcn_readfirstlane(deg[wave]);
    int start = __builtin_amdgcn_readfirstlane(off[wave]);
    float siv = s_i[wave];
    float rnv = rn[wave];
    int sub = lane & (LPR - 1);
    int g   = lane >> L2LPR;                   // which edge within a load instr
    const unsigned char* hbase = Hf8 + sub * 8;  // 8 fp8 channels per lane

    const float qc  = 1.0f / (1.0f + __expf(-(1.0f / 15.0f)));
    const float lq  = __logf(qc);
    const float l1q = __logf(1.0f - qc);

    f32x2 acc[4];
#pragma unroll
    for (int k = 0; k < 4; k++) acc[k] = {0.f, 0.f};

    for (int base = 0; base < d; base += 64) {
      // ---- metadata phase: lanes 0..63 each own one edge ----
      int ee = base + lane;
      unsigned int ce = csr[start + (ee < d ? ee : d - 1)];
      int src = (int)(ce & 0xffffu);
      float sj = s_j[src];
      float lg = siv + sj;
      lg = lg > 0.f ? lg : 0.2f * lg;                 // leaky_relu
      float pv = 1.0f / (1.0f + __expf(-lg));        // sigmoid
      pv = fminf(fmaxf(pv, 0.01f), 0.99f);           // clip
      if (ee < d)
        skl += pv * (__logf(pv) - lq) + (1.0f - pv) * (__logf(1.0f - pv) - l1q);
      float wval = (ee < d) ? pv * rnv : 0.f;        // w=0 kills clamped tail edges

      // ---- gather loop: consume up to 64 edges via register shuffles ----
      int cnt = min(d - base, 64);
      for (int c0 = 0; c0 < cnt; c0 += U) {
        int srcl[NL];
        float wl[NL];
#pragma unroll
        for (int l = 0; l < NL; l++) {
          int idx = c0 + l * EPL + g;                // <= 63 by construction
          srcl[l] = __shfl(src, idx);
          wl[l]   = __shfl(wval, idx);
        }
        u32x2 hv[NL];
#pragma unroll
        for (int l = 0; l < NL; l++)
          hv[l] = *(const u32x2*)(hbase + (size_t)srcl[l] * M);
#pragma unroll
        for (int l = 0; l < NL; l++) {
          f32x2 wv = {wl[l], wl[l]};
          f32x2 d0 = __builtin_amdgcn_cvt_pk_f32_fp8((int)hv[l][0], false);
          f32x2 d1 = __builtin_amdgcn_cvt_pk_f32_fp8((int)hv[l][0], true);
          f32x2 d2 = __builtin_amdgcn_cvt_pk_f32_fp8((int)hv[l][1], false);
          f32x2 d3 = __builtin_amdgcn_cvt_pk_f32_fp8((int)hv[l][1], true);
          acc[0] = d0 * wv + acc[0];
          acc[1] = d1 * wv + acc[1];
          acc[2] = d2 * wv + acc[2];
          acc[3] = d3 * wv + acc[3];
        }
      }
    }

    // combine lane-groups (same channels, different edges)
#pragma unroll
    for (int o = LPR; o < 64; o <<= 1) {
#pragma unroll
      for (int j = 0; j < 4; j++) {
        acc[j][0] += __shfl_xor(acc[j][0], o);
        acc[j][1] += __shfl_xor(acc[j][1], o);
      }
    }

    if (lane < LPR) {
      int ch0 = sub * 8;
      if (ch0 < C) {                           // mu channels
        f32x4 mv[2];
#pragma unroll
        for (int j = 0; j < 4; j++) {
          float a0 = acc[j][0] + bias[ch0 + 2 * j];
          float a1 = acc[j][1] + bias[ch0 + 2 * j + 1];
          ixz += 0.5f * (a0 * a0 + a1 * a1) - 1.0f;
          mv[j >> 1][(j & 1) * 2]     = a0;
          mv[j >> 1][(j & 1) * 2 + 1] = a1;
        }
        *(f32x4*)(mu + (size_t)wave * C + ch0)     = mv[0];
        *(f32x4*)(mu + (size_t)wave * C + ch0 + 4) = mv[1];
      } else {                                 // std channels: softplus ixz
#pragma unroll
        for (int j = 0; j < 4; j++) {
#pragma unroll
          for (int h = 0; h < 2; h++) {
            float a = acc[j][h] + bias[ch0 + 2 * j + h];
            float sp = (a > 20.f) ? a : log1pf(__expf(a));  // softplus
            sp += 1e-10f;
            ixz += -__logf(sp) + 0.5f * sp * sp;
          }
        }
      }
    }
  }
#pragma unroll
  for (int o = 32; o > 0; o >>= 1) {
    ixz += __shfl_xor(ixz, o);
    skl += __shfl_xor(skl, o);
  }
  if (lane == 0) { f32x2 r; r[0] = ixz; r[1] = skl; red[wid] = r; }
  __syncthreads();
  if (threadIdx.x == 0) {
    f32x2 pr = red[0] + red[1] + red[2] + red[3];
    part[t * ABLK + blockIdx.x] = pr;
  }
}

// ---------------- layer-2 temporal fusion -> final output (fp32) ----------------
__global__ void fuse2_kernel(const float* __restrict__ mu0, const float* __restrict__ mu1,
                             float* __restrict__ out, int n) {
  int i = blockIdx.x * blockDim.x + threadIdx.x;
  if (i < n) {
    float m0 = mu0[i], m1 = mu1[i];
    out[i] = m0;
    out[n + i] = 0.4f * m0 + 0.2f * m1;
  }
}

// ---------------- final reduction of per-block partials -> scalars ----------------
__global__ __launch_bounds__(1024) void reduce_kernel(const f32x2* __restrict__ p1,
                                                      const f32x2* __restrict__ p2,
                                                      float* __restrict__ out2) {
  __shared__ float ri[16], rs[16];
  float ixz = 0.f, skl = 0.f;
  for (int i = threadIdx.x; i < 2 * ABLK; i += 1024) {
    f32x2 a = p1[i], b = p2[i];
    ixz += a[0] + b[0];
    skl += a[1] + b[1];
  }
  int lane = threadIdx.x & 63, wid = threadIdx.x >> 6;
#pragma unroll
  for (int o = 32; o > 0; o >>= 1) {
    ixz += __shfl_xor(ixz, o);
    skl += __shfl_xor(skl, o);
  }
  if (lane == 0) { ri[wid] = ixz; rs[wid] = skl; }
  __syncthreads();
  if (threadIdx.x == 0) {
    float si = 0.f, ss = 0.f;
    for (int w = 0; w < 16; w++) { si += ri[w]; ss += rs[w]; }
    out2[0] = si / (4.0f * (float)N_NODES);
    out2[1] = ss / (4.0f * (float)N_EDGES);
  }
}

extern "C" void kernel_launch(void* const* d_in, const int* in_sizes, int n_in,
                              void* d_out, int out_size, void* d_ws, size_t ws_size,
                              hipStream_t stream) {
  const float* x_all = (const float*)d_in[0];
  const int* ei      = (const int*)d_in[1];
  const float* W1    = (const float*)d_in[2];
  const float* att1  = (const float*)d_in[3];
  const float* b1    = (const float*)d_in[4];
  const float* W2    = (const float*)d_in[5];
  const float* att2  = (const float*)d_in[6];
  const float* b2    = (const float*)d_in[7];
  float* out         = (float*)d_out;

  char* ws = (char*)d_ws;
  size_t off = 0;
  auto alloc = [&](size_t bytes) {
    char* p = ws + off;
    off = (off + bytes + 255) & ~(size_t)255;
    return p;
  };
  unsigned short* wt1  = (unsigned short*)alloc(256 * 128 * sizeof(short));
  unsigned short* wt2  = (unsigned short*)alloc(128 * 128 * sizeof(short));
  unsigned char* hf8_0 = (unsigned char*)alloc((size_t)N_NODES * 256);
  unsigned char* hf8_1 = (unsigned char*)alloc((size_t)N_NODES * 256);
  float* si0   = (float*)alloc(N_NODES * sizeof(float));
  float* si1   = (float*)alloc(N_NODES * sizeof(float));
  float* sj0   = (float*)alloc(N_NODES * sizeof(float));
  float* sj1   = (float*)alloc(N_NODES * sizeof(float));
  float* mu1_0 = (float*)alloc((size_t)N_NODES * 128 * sizeof(float));
  float* mu1_1 = (float*)alloc((size_t)N_NODES * 128 * sizeof(float));
  // mu2 buffers alias mu1_0's region: gemm2 reads mu1 BEFORE aggr2 writes mu2
  // (stream-ordered); fuse2 reads mu2 afterwards.
  float* mu2_0 = mu1_0;
  float* mu2_1 = mu1_0 + (size_t)N_NODES * 64;
  // deg arrays contiguous -> single memset
  int* degbase  = (int*)alloc(2 * N_NODES * 4);
  int* degp[2]  = {degbase, degbase + N_NODES};
  int* offp[2]  = {(int*)alloc(N_NODES * 4), (int*)alloc(N_NODES * 4)};
  int* curp[2]  = {(int*)alloc(N_NODES * 4), (int*)alloc(N_NODES * 4)};
  float* rnp[2] = {(float*)alloc(N_NODES * 4), (float*)alloc(N_NODES * 4)};
  unsigned int* csrp[2] = {(unsigned int*)alloc((size_t)N_EDGES * 4),
                           (unsigned int*)alloc((size_t)N_EDGES * 4)};
  int* bsums   = (int*)alloc(2 * SB * sizeof(int));
  f32x2* part1 = (f32x2*)alloc(2 * ABLK * sizeof(f32x2));
  f32x2* part2 = (f32x2*)alloc(2 * ABLK * sizeof(f32x2));

  hipMemsetAsync(degbase, 0, 2 * N_NODES * 4, stream);

  prep_kernel<<<(2 * N_EDGES + 255) / 256, 256, 0, stream>>>(W1, wt1, W2, wt2,
                                                             ei, degp[0], degp[1], N_EDGES);
  dim3 sgrid(SB, 2);
  bsum_kernel<<<sgrid, 256, 0, stream>>>(degp[0], degp[1], rnp[0], rnp[1], bsums, N_NODES);
  bscan_kernel<<<1, 128, 0, stream>>>(bsums);
  wout_kernel<<<sgrid, 256, 0, stream>>>(degp[0], degp[1], bsums,
                                         offp[0], curp[0], offp[1], curp[1], N_NODES);
  scatter_kernel<<<(2 * N_EDGES + 255) / 256, 256, 0, stream>>>(ei, curp[0], curp[1],
                                                                csrp[0], csrp[1], N_EDGES);

  dim3 ggrid(469, 2), agrid(ABLK, 2);

  // ---- layer 1 (C = 128, M = 256) ----
  const float* x0 = x_all;
  const float* x1 = x_all + (size_t)N_NODES * K_DIM;
  gemm_kernel<256, 0><<<ggrid, 256, 0, stream>>>(x0, x1, (const short*)wt1, hf8_0, hf8_1,
                                                 att1, si0, si1, sj0, sj1, N_NODES);
  aggr_kernel<256><<<agrid, 256, 0, stream>>>(hf8_0, hf8_1, csrp[0], csrp[1], offp[0], offp[1],
                                              degp[0], degp[1], rnp[0], rnp[1],
                                              si0, si1, sj0, sj1, b1, mu1_0, mu1_1, part1, N_NODES);

  // ---- layer 2 (C = 64, M = 128): A-fragment fused from mu1 inline ----
  gemm_kernel<128, 1><<<ggrid, 256, 0, stream>>>(mu1_0, mu1_1, (const short*)wt2, hf8_0, hf8_1,
                                                 att2, si0, si1, sj0, sj1, N_NODES);
  aggr_kernel<128><<<agrid, 256, 0, stream>>>(hf8_0, hf8_1, csrp[0], csrp[1], offp[0], offp[1],
                                              degp[0], degp[1], rnp[0], rnp[1],
                                              si0, si1, sj0, sj1, b2, mu2_0, mu2_1, part2, N_NODES);
  fuse2_kernel<<<(N_NODES * 64 + 255) / 256, 256, 0, stream>>>(mu2_0, mu2_1, out, N_NODES * 64);
  reduce_kernel<<<1, 1024, 0, stream>>>(part1, part2, out + (size_t)2 * N_NODES * 64);
}